// Round 1
// baseline (746.527 us; speedup 1.0000x reference)
//
#include <hip/hip_runtime.h>
#include <math.h>

#define N_RNA 4096
#define N_ATAC 8192
#define IN_C 256
#define HID 128
#define DH 64
#define NH 2
#define TOPK 10
#define NEG_INF -3.402823466e38f

// ---------------------------------------------------------------- top-k insert
__device__ __forceinline__ void topk_insert(float (&tv)[10], int (&ti)[10],
                                            float &mn, int &ms, float lv, int a) {
#pragma unroll
    for (int s = 0; s < 10; ++s) {
        if (s == ms) { tv[s] = lv; ti[s] = a; }
    }
    mn = tv[0]; ms = 0;
#pragma unroll
    for (int s = 1; s < 10; ++s) {
        if (tv[s] < mn) { mn = tv[s]; ms = s; }
    }
}

// ---------------------------------------------------------------- K0: fold output projections
// Wr1 = Wor@Wdr_top, Wr2 = Wsr@Wdr_bot, br = bdr + bor@Wdr_top + bsr@Wdr_bot (same for atac)
__global__ __launch_bounds__(256) void fuse_weights(
    const float* __restrict__ Wor, const float* __restrict__ bor,
    const float* __restrict__ Woa, const float* __restrict__ boa,
    const float* __restrict__ Wsr, const float* __restrict__ bsr,
    const float* __restrict__ Wsa, const float* __restrict__ bsa,
    const float* __restrict__ Wdr, const float* __restrict__ bdr,
    const float* __restrict__ Wda, const float* __restrict__ bda,
    float* __restrict__ Wr1, float* __restrict__ Wr2, float* __restrict__ br,
    float* __restrict__ Wa1, float* __restrict__ Wa2, float* __restrict__ ba) {
    int f = blockIdx.x * 256 + threadIdx.x;
    if (f < 16384) {
        int i = f >> 7, j = f & 127; float s = 0.f;
        for (int t = 0; t < 128; ++t) s += Wor[i * 128 + t] * Wdr[t * 128 + j];
        Wr1[f] = s;
    } else if (f < 49152) {
        int e = f - 16384; int i = e >> 7, j = e & 127; float s = 0.f;
        for (int t = 0; t < 128; ++t) s += Wsr[i * 128 + t] * Wdr[(128 + t) * 128 + j];
        Wr2[e] = s;
    } else if (f < 65536) {
        int e = f - 49152; int i = e >> 7, j = e & 127; float s = 0.f;
        for (int t = 0; t < 128; ++t) s += Woa[i * 128 + t] * Wda[t * 128 + j];
        Wa1[e] = s;
    } else if (f < 98304) {
        int e = f - 65536; int i = e >> 7, j = e & 127; float s = 0.f;
        for (int t = 0; t < 128; ++t) s += Wsa[i * 128 + t] * Wda[(128 + t) * 128 + j];
        Wa2[e] = s;
    } else if (f < 98432) {
        int j = f - 98304; float s = bdr[j];
        for (int t = 0; t < 128; ++t) s += bor[t] * Wdr[t * 128 + j] + bsr[t] * Wdr[(128 + t) * 128 + j];
        br[j] = s;
    } else if (f < 98560) {
        int j = f - 98432; float s = bda[j];
        for (int t = 0; t < 128; ++t) s += boa[t] * Wda[t * 128 + j] + bsa[t] * Wda[(128 + t) * 128 + j];
        ba[j] = s;
    }
}

// ---------------------------------------------------------------- K1: projections
// C = X@W + b.  cfg 0: q (transposed out), 1: v_r, 2: k (transposed out), 3: v_a
__global__ __launch_bounds__(256) void proj_gemm(
    const float* __restrict__ x_rna, const float* __restrict__ x_atac,
    const float* __restrict__ Wq, const float* __restrict__ bq,
    const float* __restrict__ Wk, const float* __restrict__ bk,
    const float* __restrict__ Wvr, const float* __restrict__ bvr,
    const float* __restrict__ Wva, const float* __restrict__ bva,
    float* __restrict__ qT, float* __restrict__ kT,
    float* __restrict__ v_r, float* __restrict__ v_a) {
    int cfg = blockIdx.y;
    const float *X, *W, *B; float* C; int M; bool wT;
    if (cfg == 0)      { X = x_rna;  W = Wq;  B = bq;  C = qT;  M = N_RNA;  wT = true;  }
    else if (cfg == 1) { X = x_rna;  W = Wvr; B = bvr; C = v_r; M = N_RNA;  wT = false; }
    else if (cfg == 2) { X = x_atac; W = Wk;  B = bk;  C = kT;  M = N_ATAC; wT = true;  }
    else               { X = x_atac; W = Wva; B = bva; C = v_a; M = N_ATAC; wT = false; }
    int r0 = blockIdx.x * 64;
    if (r0 >= M) return;

    __shared__ __align__(16) float x_s[64][33];
    __shared__ __align__(16) float w_s[32][128];
    int tid = threadIdx.x;
    int rg = tid >> 4, cg = tid & 15;

    float acc[4][8];
#pragma unroll
    for (int i = 0; i < 4; ++i)
#pragma unroll
        for (int j = 0; j < 8; ++j) acc[i][j] = 0.f;

    for (int k0 = 0; k0 < IN_C; k0 += 32) {
        __syncthreads();
        for (int i4 = tid; i4 < 512; i4 += 256) {           // stage X 64x32
            int rr = i4 >> 3, kq = i4 & 7;
            float4 v = *(const float4*)&X[(size_t)(r0 + rr) * IN_C + k0 + kq * 4];
            x_s[rr][kq * 4 + 0] = v.x; x_s[rr][kq * 4 + 1] = v.y;
            x_s[rr][kq * 4 + 2] = v.z; x_s[rr][kq * 4 + 3] = v.w;
        }
        for (int i4 = tid; i4 < 1024; i4 += 256) {          // stage W 32x128
            int kk = i4 >> 5, cq = i4 & 31;
            float4 v = *(const float4*)&W[(size_t)(k0 + kk) * HID + cq * 4];
            *(float4*)&w_s[kk][cq * 4] = v;
        }
        __syncthreads();
#pragma unroll 8
        for (int kk = 0; kk < 32; ++kk) {
            float x0 = x_s[rg * 4 + 0][kk], x1 = x_s[rg * 4 + 1][kk];
            float x2 = x_s[rg * 4 + 2][kk], x3 = x_s[rg * 4 + 3][kk];
            float4 wa = *(const float4*)&w_s[kk][cg * 4];
            float4 wb = *(const float4*)&w_s[kk][64 + cg * 4];
            acc[0][0] += x0 * wa.x; acc[0][1] += x0 * wa.y; acc[0][2] += x0 * wa.z; acc[0][3] += x0 * wa.w;
            acc[0][4] += x0 * wb.x; acc[0][5] += x0 * wb.y; acc[0][6] += x0 * wb.z; acc[0][7] += x0 * wb.w;
            acc[1][0] += x1 * wa.x; acc[1][1] += x1 * wa.y; acc[1][2] += x1 * wa.z; acc[1][3] += x1 * wa.w;
            acc[1][4] += x1 * wb.x; acc[1][5] += x1 * wb.y; acc[1][6] += x1 * wb.z; acc[1][7] += x1 * wb.w;
            acc[2][0] += x2 * wa.x; acc[2][1] += x2 * wa.y; acc[2][2] += x2 * wa.z; acc[2][3] += x2 * wa.w;
            acc[2][4] += x2 * wb.x; acc[2][5] += x2 * wb.y; acc[2][6] += x2 * wb.z; acc[2][7] += x2 * wb.w;
            acc[3][0] += x3 * wa.x; acc[3][1] += x3 * wa.y; acc[3][2] += x3 * wa.z; acc[3][3] += x3 * wa.w;
            acc[3][4] += x3 * wb.x; acc[3][5] += x3 * wb.y; acc[3][6] += x3 * wb.z; acc[3][7] += x3 * wb.w;
        }
    }
    float bv[8];
#pragma unroll
    for (int j = 0; j < 8; ++j) {
        int c = (j < 4) ? (cg * 4 + j) : (64 + cg * 4 + (j - 4));
        bv[j] = B[c];
    }
    if (wT) {
#pragma unroll
        for (int i = 0; i < 4; ++i)
#pragma unroll
            for (int j = 0; j < 8; ++j) {
                int c = (j < 4) ? (cg * 4 + j) : (64 + cg * 4 + (j - 4));
                C[(size_t)c * M + r0 + rg * 4 + i] = acc[i][j] + bv[j];
            }
    } else {
#pragma unroll
        for (int i = 0; i < 4; ++i) {
            int r = r0 + rg * 4 + i;
            float4 oa = make_float4(acc[i][0] + bv[0], acc[i][1] + bv[1], acc[i][2] + bv[2], acc[i][3] + bv[3]);
            float4 ob = make_float4(acc[i][4] + bv[4], acc[i][5] + bv[5], acc[i][6] + bv[6], acc[i][7] + bv[7]);
            *(float4*)&C[(size_t)r * HID + cg * 4] = oa;
            *(float4*)&C[(size_t)r * HID + 64 + cg * 4] = ob;
        }
    }
}

// ---------------------------------------------------------------- zero fill
__global__ __launch_bounds__(256) void zero_buf(float* __restrict__ p) {
    int i = blockIdx.x * 256 + threadIdx.x;
    *(float4*)&p[(size_t)i * 4] = make_float4(0.f, 0.f, 0.f, 0.f);
}

// ---------------------------------------------------------------- K2: fused QK^T + mask + per-half top-10
// grid (128 r-tiles, 2 a-halves, 2 heads), block 256.  RT=32 rows, AT=128 a per tile.
__global__ __launch_bounds__(256) void attn_topk(
    const float* __restrict__ qT, const float* __restrict__ kT,
    const float* __restrict__ mask,
    float* __restrict__ part_v, int* __restrict__ part_i) {
    __shared__ __align__(16) float smem[10496];   // k_s[64][132] | q_s[64][32]; reused for merge
    float* k_s = smem;
    float* q_s = smem + 64 * 132;

    int h = blockIdx.z, half = blockIdx.y, rt = blockIdx.x;
    int r0 = rt * 32;
    int abase = half * 4096;
    int tid = threadIdx.x;
    int rg = tid >> 4, ag = tid & 15;

    for (int i = tid; i < 64 * 32; i += 256) {            // stage q (transposed: [d][r])
        int d = i >> 5, rr = i & 31;
        q_s[d * 32 + rr] = qT[(size_t)(h * 64 + d) * N_RNA + r0 + rr];
    }

    float tv[2][10]; int ti[2][10]; float mn[2]; int ms[2];
#pragma unroll
    for (int rr = 0; rr < 2; ++rr) {
        mn[rr] = NEG_INF; ms[rr] = 0;
#pragma unroll
        for (int s = 0; s < 10; ++s) { tv[rr][s] = NEG_INF; ti[rr][s] = 0; }
    }

    for (int at = 0; at < 32; ++at) {
        int a0 = abase + at * 128;
        __syncthreads();
        for (int i4 = tid; i4 < 2048; i4 += 256) {        // stage k tile [d][a] (pad 4)
            int d = i4 >> 5, a4 = i4 & 31;
            float4 v = *(const float4*)&kT[(size_t)(h * 64 + d) * N_ATAC + a0 + a4 * 4];
            *(float4*)&k_s[d * 132 + a4 * 4] = v;
        }
        __syncthreads();

        float acc[2][8];
#pragma unroll
        for (int rr = 0; rr < 2; ++rr)
#pragma unroll
            for (int j = 0; j < 8; ++j) acc[rr][j] = 0.f;

#pragma unroll 4
        for (int d = 0; d < 64; ++d) {
            float qa = q_s[d * 32 + rg * 2];
            float qb = q_s[d * 32 + rg * 2 + 1];
            float4 ka = *(const float4*)&k_s[d * 132 + ag * 4];
            float4 kb = *(const float4*)&k_s[d * 132 + 64 + ag * 4];
            acc[0][0] += qa * ka.x; acc[0][1] += qa * ka.y; acc[0][2] += qa * ka.z; acc[0][3] += qa * ka.w;
            acc[0][4] += qa * kb.x; acc[0][5] += qa * kb.y; acc[0][6] += qa * kb.z; acc[0][7] += qa * kb.w;
            acc[1][0] += qb * ka.x; acc[1][1] += qb * ka.y; acc[1][2] += qb * ka.z; acc[1][3] += qb * ka.w;
            acc[1][4] += qb * kb.x; acc[1][5] += qb * kb.y; acc[1][6] += qb * kb.z; acc[1][7] += qb * kb.w;
        }

#pragma unroll
        for (int rr = 0; rr < 2; ++rr) {
            int r = r0 + rg * 2 + rr;
            const float* mrow = mask + (size_t)r * N_ATAC + a0;
            float4 m0 = *(const float4*)&mrow[ag * 4];
            float4 m1 = *(const float4*)&mrow[64 + ag * 4];
            float lv_[8];
            lv_[0] = acc[rr][0] * m0.x; lv_[1] = acc[rr][1] * m0.y;
            lv_[2] = acc[rr][2] * m0.z; lv_[3] = acc[rr][3] * m0.w;
            lv_[4] = acc[rr][4] * m1.x; lv_[5] = acc[rr][5] * m1.y;
            lv_[6] = acc[rr][6] * m1.z; lv_[7] = acc[rr][7] * m1.w;
#pragma unroll
            for (int j = 0; j < 8; ++j) {
                int aidx = a0 + ((j < 4) ? (ag * 4 + j) : (64 + ag * 4 + (j - 4)));
                float lv = lv_[j];
                if (lv > mn[rr]) topk_insert(tv[rr], ti[rr], mn[rr], ms[rr], lv, aidx);
            }
        }
    }

    // merge 16 a-groups per row -> per-(row,half) top-10
    __syncthreads();
    float* cv = smem;                     // [32][16][10] floats
    int* ci = (int*)(smem + 5120);        // [32][16][10] ints
#pragma unroll
    for (int rr = 0; rr < 2; ++rr) {
        int row = rg * 2 + rr;
        int base = (row * 16 + ag) * 10;
#pragma unroll
        for (int s = 0; s < 10; ++s) { cv[base + s] = tv[rr][s]; ci[base + s] = ti[rr][s]; }
    }
    __syncthreads();
    if (tid < 32) {
        int row = tid;
        float mv[10]; int mi[10];
#pragma unroll
        for (int s = 0; s < 10; ++s) { mv[s] = cv[row * 160 + s]; mi[s] = ci[row * 160 + s]; }
        float m2 = mv[0]; int s2 = 0;
#pragma unroll
        for (int s = 1; s < 10; ++s) if (mv[s] < m2) { m2 = mv[s]; s2 = s; }
        for (int t = 1; t < 16; ++t) {
            int base = row * 160 + t * 10;
#pragma unroll
            for (int s = 0; s < 10; ++s) {
                float lv = cv[base + s]; int a = ci[base + s];
                if (lv > m2) topk_insert(mv, mi, m2, s2, lv, a);
            }
        }
        int pr = ((h * N_RNA + r0 + row) * 2 + half) * 16;
#pragma unroll
        for (int s = 0; s < 10; ++s) { part_v[pr + s] = mv[s]; part_i[pr + s] = mi[s]; }
    }
}

// ---------------------------------------------------------------- K2b: merge halves + sigmoid + softmax + threshold
__global__ __launch_bounds__(256) void topk_finalize(
    const float* __restrict__ part_v, const int* __restrict__ part_i,
    float* __restrict__ sel_w, int* __restrict__ sel_i) {
    int p = blockIdx.x * 256 + threadIdx.x;   // (h*4096 + r)
    if (p >= NH * N_RNA) return;
    const float* pv = part_v + (size_t)p * 32;
    const int* pi = part_i + (size_t)p * 32;
    float mv[10]; int mi[10];
#pragma unroll
    for (int s = 0; s < 10; ++s) { mv[s] = pv[s]; mi[s] = pi[s]; }
    float mn = mv[0]; int ms = 0;
#pragma unroll
    for (int s = 1; s < 10; ++s) if (mv[s] < mn) { mn = mv[s]; ms = s; }
#pragma unroll
    for (int s = 0; s < 10; ++s) {
        float lv = pv[16 + s]; int a = pi[16 + s];
        if (lv > mn) topk_insert(mv, mi, mn, ms, lv, a);
    }
    float sg[10]; float es[10]; float sum = 0.f;
#pragma unroll
    for (int s = 0; s < 10; ++s) {
        sg[s] = 1.0f / (1.0f + expf(-mv[s]));
        es[s] = expf(sg[s]);
        sum += es[s];
    }
    float inv = 1.0f / sum;
    int base = p * 16;
#pragma unroll
    for (int s = 0; s < 10; ++s) {
        float w = es[s] * inv;
        if (!(sg[s] > 0.8f)) w = 0.f;
        sel_w[base + s] = w;
        sel_i[base + s] = mi[s];
    }
}

// ---------------------------------------------------------------- K3a: rna_agg gather
__global__ __launch_bounds__(256) void rna_gather(
    const float* __restrict__ sel_w, const int* __restrict__ sel_i,
    const float* __restrict__ v_a, float* __restrict__ rna_agg) {
    int tid = threadIdx.x;
    int r = blockIdx.x * 64 + (tid >> 2);
    int cq = tid & 3; int c0 = cq * 32; int h = cq >> 1;
    int base = (h * N_RNA + r) * 16;
    float4 acc[8];
#pragma unroll
    for (int j = 0; j < 8; ++j) acc[j] = make_float4(0.f, 0.f, 0.f, 0.f);
    for (int i = 0; i < TOPK; ++i) {
        float w = sel_w[base + i];
        int idx = sel_i[base + i];
        const float4* vp = (const float4*)(v_a + (size_t)idx * HID + c0);
#pragma unroll
        for (int j = 0; j < 8; ++j) {
            float4 v = vp[j];
            acc[j].x += w * v.x; acc[j].y += w * v.y; acc[j].z += w * v.z; acc[j].w += w * v.w;
        }
    }
    float4* op = (float4*)(rna_agg + (size_t)r * HID + c0);
#pragma unroll
    for (int j = 0; j < 8; ++j) op[j] = acc[j];
}

// ---------------------------------------------------------------- K4a: atac_agg scatter (atomics)
__global__ __launch_bounds__(256) void atac_scatter(
    const float* __restrict__ sel_w, const int* __restrict__ sel_i,
    const float* __restrict__ v_r, float* __restrict__ atac_agg) {
    int wid = threadIdx.x >> 6, lane = threadIdx.x & 63;
    int p = blockIdx.x * 4 + wid;          // (h*4096 + r)
    int h = p >> 12; int r = p & 4095;
    float v = v_r[(size_t)r * HID + h * 64 + lane];
    int base = p * 16;
    for (int i = 0; i < TOPK; ++i) {
        float w = sel_w[base + i];
        if (w != 0.f) {
            int idx = sel_i[base + i];
            atomicAdd(&atac_agg[(size_t)idx * HID + h * 64 + lane], w * v);
        }
    }
}

// ---------------------------------------------------------------- K5: C = A@W1 + X@W2 + bias
__global__ __launch_bounds__(256) void out_gemm(
    const float* __restrict__ A, const float* __restrict__ X,
    const float* __restrict__ W1, const float* __restrict__ W2,
    const float* __restrict__ bias, float* __restrict__ C, int M) {
    int r = blockIdx.x * 8 + (threadIdx.x >> 5);
    int cg = threadIdx.x & 31; int c0 = cg * 4;
    float4 acc = *(const float4*)&bias[c0];
    const float* a = A + (size_t)r * HID;
#pragma unroll 4
    for (int k = 0; k < 128; ++k) {
        float av = a[k];
        float4 w = *(const float4*)&W1[(size_t)k * HID + c0];
        acc.x += av * w.x; acc.y += av * w.y; acc.z += av * w.z; acc.w += av * w.w;
    }
    const float* x = X + (size_t)r * IN_C;
#pragma unroll 4
    for (int k = 0; k < 256; ++k) {
        float xv = x[k];
        float4 w = *(const float4*)&W2[(size_t)k * HID + c0];
        acc.x += xv * w.x; acc.y += xv * w.y; acc.z += xv * w.z; acc.w += xv * w.w;
    }
    *(float4*)&C[(size_t)r * HID + c0] = acc;
}

// ---------------------------------------------------------------- launch
extern "C" void kernel_launch(void* const* d_in, const int* in_sizes, int n_in,
                              void* d_out, int out_size, void* d_ws, size_t ws_size,
                              hipStream_t stream) {
    const float* x_rna = (const float*)d_in[0];
    const float* x_atac = (const float*)d_in[1];
    const float* mask = (const float*)d_in[2];
    const float* Wq = (const float*)d_in[3];  const float* bq = (const float*)d_in[4];
    const float* Wk = (const float*)d_in[5];  const float* bk = (const float*)d_in[6];
    const float* Wvr = (const float*)d_in[7]; const float* bvr = (const float*)d_in[8];
    const float* Wva = (const float*)d_in[9]; const float* bva = (const float*)d_in[10];
    const float* Wor = (const float*)d_in[11]; const float* bor = (const float*)d_in[12];
    const float* Woa = (const float*)d_in[13]; const float* boa = (const float*)d_in[14];
    const float* Wsr = (const float*)d_in[15]; const float* bsr = (const float*)d_in[16];
    const float* Wsa = (const float*)d_in[17]; const float* bsa = (const float*)d_in[18];
    const float* Wdr = (const float*)d_in[19]; const float* bdr = (const float*)d_in[20];
    const float* Wda = (const float*)d_in[21]; const float* bda = (const float*)d_in[22];

    float* out_r = (float*)d_out;
    float* out_a = out_r + N_RNA * HID;

    float* ws = (float*)d_ws;
    float* qT = ws;                       // 128 x 4096
    float* kT = qT + 524288;              // 128 x 8192
    float* v_r = kT + 1048576;            // 4096 x 128
    float* v_a = v_r + 524288;            // 8192 x 128
    float* Wr1 = v_a + 1048576;           // 128 x 128
    float* Wr2 = Wr1 + 16384;             // 256 x 128
    float* brf = Wr2 + 32768;             // 128
    float* Wa1 = brf + 128;               // 128 x 128
    float* Wa2 = Wa1 + 16384;             // 256 x 128
    float* baf = Wa2 + 32768;             // 128
    float* part_v = baf + 128;            // [2][4096][2][16]
    int* part_i = (int*)(part_v + 262144);
    float* sel_w = (float*)part_i + 262144; // [2][4096][16]
    int* sel_i = (int*)(sel_w + 131072);
    float* rna_agg = (float*)sel_i + 131072; // 4096 x 128
    float* atac_agg = rna_agg + 524288;      // 8192 x 128

    hipLaunchKernelGGL(fuse_weights, dim3(386), dim3(256), 0, stream,
                       Wor, bor, Woa, boa, Wsr, bsr, Wsa, bsa, Wdr, bdr, Wda, bda,
                       Wr1, Wr2, brf, Wa1, Wa2, baf);
    hipLaunchKernelGGL(proj_gemm, dim3(128, 4), dim3(256), 0, stream,
                       x_rna, x_atac, Wq, bq, Wk, bk, Wvr, bvr, Wva, bva, qT, kT, v_r, v_a);
    hipLaunchKernelGGL(zero_buf, dim3(1024), dim3(256), 0, stream, atac_agg);
    hipLaunchKernelGGL(attn_topk, dim3(128, 2, 2), dim3(256), 0, stream,
                       qT, kT, mask, part_v, part_i);
    hipLaunchKernelGGL(topk_finalize, dim3(32), dim3(256), 0, stream,
                       part_v, part_i, sel_w, sel_i);
    hipLaunchKernelGGL(rna_gather, dim3(64), dim3(256), 0, stream, sel_w, sel_i, v_a, rna_agg);
    hipLaunchKernelGGL(atac_scatter, dim3(2048), dim3(256), 0, stream, sel_w, sel_i, v_r, atac_agg);
    hipLaunchKernelGGL(out_gemm, dim3(512), dim3(256), 0, stream,
                       rna_agg, x_rna, Wr1, Wr2, brf, out_r, N_RNA);
    hipLaunchKernelGGL(out_gemm, dim3(1024), dim3(256), 0, stream,
                       atac_agg, x_atac, Wa1, Wa2, baf, out_a, N_ATAC);
}

// Round 2
// 646.901 us; speedup vs baseline: 1.1540x; 1.1540x over previous
//
#include <hip/hip_runtime.h>
#include <math.h>

#define N_RNA 4096
#define N_ATAC 8192
#define IN_C 256
#define HID 128
#define NH 2
#define TOPK 10
#define CAP 32
#define NEG_INF -3.402823466e38f

typedef __attribute__((ext_vector_type(8))) short bf16x8;
typedef __attribute__((ext_vector_type(4))) float f32x4;

static __device__ __forceinline__ f32x4 mfma16(bf16x8 a, bf16x8 b, f32x4 c) {
    return __builtin_amdgcn_mfma_f32_16x16x32_bf16(a, b, c, 0, 0, 0);
}

static __device__ __forceinline__ unsigned short f2bf(float f) {
    unsigned int u = __float_as_uint(f);
    unsigned int r = (u + 0x7fffu + ((u >> 16) & 1u)) >> 16;   // RNE
    return (unsigned short)r;
}
static __device__ __forceinline__ float bf2f(unsigned short h) {
    return __uint_as_float(((unsigned int)h) << 16);
}

// ---------------------------------------------------------------- top-k insert
__device__ __forceinline__ void topk_insert(float (&tv)[10], int (&ti)[10],
                                            float &mn, int &ms, float lv, int a) {
#pragma unroll
    for (int s = 0; s < 10; ++s) {
        if (s == ms) { tv[s] = lv; ti[s] = a; }
    }
    mn = tv[0]; ms = 0;
#pragma unroll
    for (int s = 1; s < 10; ++s) {
        if (tv[s] < mn) { mn = tv[s]; ms = s; }
    }
}

// ---------------------------------------------------------------- K0: fold output projections
__global__ __launch_bounds__(256) void fuse_weights(
    const float* __restrict__ Wor, const float* __restrict__ bor,
    const float* __restrict__ Woa, const float* __restrict__ boa,
    const float* __restrict__ Wsr, const float* __restrict__ bsr,
    const float* __restrict__ Wsa, const float* __restrict__ bsa,
    const float* __restrict__ Wdr, const float* __restrict__ bdr,
    const float* __restrict__ Wda, const float* __restrict__ bda,
    float* __restrict__ Wr1, float* __restrict__ Wr2, float* __restrict__ br,
    float* __restrict__ Wa1, float* __restrict__ Wa2, float* __restrict__ ba) {
    int f = blockIdx.x * 256 + threadIdx.x;
    if (f < 16384) {
        int i = f >> 7, j = f & 127; float s = 0.f;
        for (int t = 0; t < 128; ++t) s += Wor[i * 128 + t] * Wdr[t * 128 + j];
        Wr1[f] = s;
    } else if (f < 49152) {
        int e = f - 16384; int i = e >> 7, j = e & 127; float s = 0.f;
        for (int t = 0; t < 128; ++t) s += Wsr[i * 128 + t] * Wdr[(128 + t) * 128 + j];
        Wr2[e] = s;
    } else if (f < 65536) {
        int e = f - 49152; int i = e >> 7, j = e & 127; float s = 0.f;
        for (int t = 0; t < 128; ++t) s += Woa[i * 128 + t] * Wda[t * 128 + j];
        Wa1[e] = s;
    } else if (f < 98304) {
        int e = f - 65536; int i = e >> 7, j = e & 127; float s = 0.f;
        for (int t = 0; t < 128; ++t) s += Wsa[i * 128 + t] * Wda[(128 + t) * 128 + j];
        Wa2[e] = s;
    } else if (f < 98432) {
        int j = f - 98304; float s = bdr[j];
        for (int t = 0; t < 128; ++t) s += bor[t] * Wdr[t * 128 + j] + bsr[t] * Wdr[(128 + t) * 128 + j];
        br[j] = s;
    } else if (f < 98560) {
        int j = f - 98432; float s = bda[j];
        for (int t = 0; t < 128; ++t) s += boa[t] * Wda[t * 128 + j] + bsa[t] * Wda[(128 + t) * 128 + j];
        ba[j] = s;
    }
}

// ---------------------------------------------------------------- K1: mask -> transposed bitmask
// bitsT[a][rc] bit (r&31) = mask[r][a] > 0.5.  grid (128 a-chunks, 8 r-chunks) x 256.
__global__ __launch_bounds__(256) void mask_bits(
    const float* __restrict__ mask, unsigned int* __restrict__ bitsT) {
    __shared__ unsigned int bits_s[64][16];
    int ac = blockIdx.x, rc = blockIdx.y;
    int w = threadIdx.x >> 6, lane = threadIdx.x & 63;
    int a = ac * 64 + lane;
    int rbase = rc * 512 + w * 128;
    unsigned int acc = 0;
    for (int rr = 0; rr < 128; ++rr) {
        float m = mask[(size_t)(rbase + rr) * N_ATAC + a];
        acc |= ((m > 0.5f) ? 1u : 0u) << (rr & 31);
        if ((rr & 31) == 31) { bits_s[lane][w * 4 + (rr >> 5)] = acc; acc = 0; }
    }
    __syncthreads();
    int t = threadIdx.x;
    int al = t >> 2, dw = (t & 3) * 4;
    uint4 v = *(const uint4*)&bits_s[al][dw];
    *(uint4*)&bitsT[(size_t)(ac * 64 + al) * 128 + rc * 16 + dw] = v;
}

// ---------------------------------------------------------------- K2: projections
// cfg 0: q -> bf16 hi/lo planes, 1: v_r (f32), 2: k -> bf16 hi/lo, 3: v_a (f32)
__global__ __launch_bounds__(256) void proj_gemm(
    const float* __restrict__ x_rna, const float* __restrict__ x_atac,
    const float* __restrict__ Wq, const float* __restrict__ bq,
    const float* __restrict__ Wk, const float* __restrict__ bk,
    const float* __restrict__ Wvr, const float* __restrict__ bvr,
    const float* __restrict__ Wva, const float* __restrict__ bva,
    unsigned short* __restrict__ qhi, unsigned short* __restrict__ qlo,
    unsigned short* __restrict__ khi, unsigned short* __restrict__ klo,
    float* __restrict__ v_r, float* __restrict__ v_a) {
    int cfg = blockIdx.y;
    const float *X, *W, *B; int M;
    unsigned short *hi = 0, *lo = 0; float* C = 0;
    if (cfg == 0)      { X = x_rna;  W = Wq;  B = bq;  M = N_RNA;  hi = qhi; lo = qlo; }
    else if (cfg == 1) { X = x_rna;  W = Wvr; B = bvr; M = N_RNA;  C = v_r; }
    else if (cfg == 2) { X = x_atac; W = Wk;  B = bk;  M = N_ATAC; hi = khi; lo = klo; }
    else               { X = x_atac; W = Wva; B = bva; M = N_ATAC; C = v_a; }
    int r0 = blockIdx.x * 64;
    if (r0 >= M) return;

    __shared__ __align__(16) float x_s[64][33];
    __shared__ __align__(16) float w_s[32][128];
    int tid = threadIdx.x;
    int rg = tid >> 4, cg = tid & 15;

    float acc[4][8];
#pragma unroll
    for (int i = 0; i < 4; ++i)
#pragma unroll
        for (int j = 0; j < 8; ++j) acc[i][j] = 0.f;

    for (int k0 = 0; k0 < IN_C; k0 += 32) {
        __syncthreads();
        for (int i4 = tid; i4 < 512; i4 += 256) {
            int rr = i4 >> 3, kq = i4 & 7;
            float4 v = *(const float4*)&X[(size_t)(r0 + rr) * IN_C + k0 + kq * 4];
            x_s[rr][kq * 4 + 0] = v.x; x_s[rr][kq * 4 + 1] = v.y;
            x_s[rr][kq * 4 + 2] = v.z; x_s[rr][kq * 4 + 3] = v.w;
        }
        for (int i4 = tid; i4 < 1024; i4 += 256) {
            int kk = i4 >> 5, cq = i4 & 31;
            float4 v = *(const float4*)&W[(size_t)(k0 + kk) * HID + cq * 4];
            *(float4*)&w_s[kk][cq * 4] = v;
        }
        __syncthreads();
#pragma unroll 8
        for (int kk = 0; kk < 32; ++kk) {
            float x0 = x_s[rg * 4 + 0][kk], x1 = x_s[rg * 4 + 1][kk];
            float x2 = x_s[rg * 4 + 2][kk], x3 = x_s[rg * 4 + 3][kk];
            float4 wa = *(const float4*)&w_s[kk][cg * 4];
            float4 wb = *(const float4*)&w_s[kk][64 + cg * 4];
            acc[0][0] += x0 * wa.x; acc[0][1] += x0 * wa.y; acc[0][2] += x0 * wa.z; acc[0][3] += x0 * wa.w;
            acc[0][4] += x0 * wb.x; acc[0][5] += x0 * wb.y; acc[0][6] += x0 * wb.z; acc[0][7] += x0 * wb.w;
            acc[1][0] += x1 * wa.x; acc[1][1] += x1 * wa.y; acc[1][2] += x1 * wa.z; acc[1][3] += x1 * wa.w;
            acc[1][4] += x1 * wb.x; acc[1][5] += x1 * wb.y; acc[1][6] += x1 * wb.z; acc[1][7] += x1 * wb.w;
            acc[2][0] += x2 * wa.x; acc[2][1] += x2 * wa.y; acc[2][2] += x2 * wa.z; acc[2][3] += x2 * wa.w;
            acc[2][4] += x2 * wb.x; acc[2][5] += x2 * wb.y; acc[2][6] += x2 * wb.z; acc[2][7] += x2 * wb.w;
            acc[3][0] += x3 * wa.x; acc[3][1] += x3 * wa.y; acc[3][2] += x3 * wa.z; acc[3][3] += x3 * wa.w;
            acc[3][4] += x3 * wb.x; acc[3][5] += x3 * wb.y; acc[3][6] += x3 * wb.z; acc[3][7] += x3 * wb.w;
        }
    }
    float bv[8];
#pragma unroll
    for (int j = 0; j < 8; ++j) {
        int c = (j < 4) ? (cg * 4 + j) : (64 + cg * 4 + (j - 4));
        bv[j] = B[c];
    }
    if (hi) {
        // bf16 hi/lo split planes, row-major [M][128]
#pragma unroll
        for (int i = 0; i < 4; ++i) {
            int r = r0 + rg * 4 + i;
            ushort4 h0, l0, h1, l1;
            float va[8];
#pragma unroll
            for (int j = 0; j < 8; ++j) va[j] = acc[i][j] + bv[j];
            h0.x = f2bf(va[0]); h0.y = f2bf(va[1]); h0.z = f2bf(va[2]); h0.w = f2bf(va[3]);
            h1.x = f2bf(va[4]); h1.y = f2bf(va[5]); h1.z = f2bf(va[6]); h1.w = f2bf(va[7]);
            l0.x = f2bf(va[0] - bf2f(h0.x)); l0.y = f2bf(va[1] - bf2f(h0.y));
            l0.z = f2bf(va[2] - bf2f(h0.z)); l0.w = f2bf(va[3] - bf2f(h0.w));
            l1.x = f2bf(va[4] - bf2f(h1.x)); l1.y = f2bf(va[5] - bf2f(h1.y));
            l1.z = f2bf(va[6] - bf2f(h1.z)); l1.w = f2bf(va[7] - bf2f(h1.w));
            *(ushort4*)&hi[(size_t)r * 128 + cg * 4] = h0;
            *(ushort4*)&hi[(size_t)r * 128 + 64 + cg * 4] = h1;
            *(ushort4*)&lo[(size_t)r * 128 + cg * 4] = l0;
            *(ushort4*)&lo[(size_t)r * 128 + 64 + cg * 4] = l1;
        }
    } else {
#pragma unroll
        for (int i = 0; i < 4; ++i) {
            int r = r0 + rg * 4 + i;
            float4 oa = make_float4(acc[i][0] + bv[0], acc[i][1] + bv[1], acc[i][2] + bv[2], acc[i][3] + bv[3]);
            float4 ob = make_float4(acc[i][4] + bv[4], acc[i][5] + bv[5], acc[i][6] + bv[6], acc[i][7] + bv[7]);
            *(float4*)&C[(size_t)r * HID + cg * 4] = oa;
            *(float4*)&C[(size_t)r * HID + 64 + cg * 4] = ob;
        }
    }
}

// ---------------------------------------------------------------- zero fill
__global__ __launch_bounds__(256) void zero_buf(float* __restrict__ p) {
    int i = blockIdx.x * 256 + threadIdx.x;
    *(float4*)&p[(size_t)i * 4] = make_float4(0.f, 0.f, 0.f, 0.f);
}

// ---------------------------------------------------------------- K3: two-phase MFMA attention top-k
// grid (8 = h*4+quarter, 128 rtiles), block 256 (4 waves).
// Phase A: per-(row, bucket) masked max -> tau_row = 10th largest of 64 bucket maxes (<= true v10).
// Phase B: rescan, append survivors (bit && val >= tau) to global lists.
__global__ __launch_bounds__(256, 4) void attn_twophase(
    const unsigned short* __restrict__ qhi, const unsigned short* __restrict__ qlo,
    const unsigned short* __restrict__ khi, const unsigned short* __restrict__ klo,
    const unsigned int* __restrict__ bitsT,
    int* __restrict__ scnt, float* __restrict__ sval, int* __restrict__ sidx) {
    int hq = blockIdx.x; int h = hq >> 2, qtr = hq & 3;
    int rt = blockIdx.y; int r0 = rt * 32;
    int tid = threadIdx.x;
    int w = tid >> 6, lane = tid & 63;
    int n = lane & 15, quad = lane >> 4;
    int aw0 = qtr * 2048 + w * 512;
    int pbase = (h * N_RNA + r0) * 4 + qtr;

    __shared__ float bmax[32][65];
    __shared__ float taus[32];

    // Preload A-frags (reused for the whole a-scan, both phases)
    bf16x8 Ah[2][2], Al[2][2];
#pragma unroll
    for (int mt = 0; mt < 2; ++mt)
#pragma unroll
        for (int c = 0; c < 2; ++c) {
            size_t off = (size_t)(r0 + mt * 16 + n) * 128 + h * 64 + c * 32 + quad * 8;
            Ah[mt][c] = *(const bf16x8*)(qhi + off);
            Al[mt][c] = *(const bf16x8*)(qlo + off);
        }

    float mx[8];
#pragma unroll
    for (int i = 0; i < 8; ++i) mx[i] = 0.f;
    float tau[8];
#pragma unroll
    for (int i = 0; i < 8; ++i) tau[i] = 0.f;

    for (int phase = 0; phase < 2; ++phase) {
#pragma unroll 2
        for (int sub = 0; sub < 32; ++sub) {
            int a = aw0 + sub * 16 + n;
            size_t koff = (size_t)a * 128 + h * 64 + quad * 8;
            bf16x8 Bh0 = *(const bf16x8*)(khi + koff);
            bf16x8 Bh1 = *(const bf16x8*)(khi + koff + 32);
            bf16x8 Bl0 = *(const bf16x8*)(klo + koff);
            bf16x8 Bl1 = *(const bf16x8*)(klo + koff + 32);
            unsigned int bits = bitsT[(size_t)a * 128 + rt];

            f32x4 ac0 = {0.f, 0.f, 0.f, 0.f}, ac1 = {0.f, 0.f, 0.f, 0.f};
            ac0 = mfma16(Ah[0][0], Bh0, ac0); ac1 = mfma16(Ah[1][0], Bh0, ac1);
            ac0 = mfma16(Ah[0][1], Bh1, ac0); ac1 = mfma16(Ah[1][1], Bh1, ac1);
            ac0 = mfma16(Ah[0][0], Bl0, ac0); ac1 = mfma16(Ah[1][0], Bl0, ac1);
            ac0 = mfma16(Ah[0][1], Bl1, ac0); ac1 = mfma16(Ah[1][1], Bl1, ac1);
            ac0 = mfma16(Al[0][0], Bh0, ac0); ac1 = mfma16(Al[1][0], Bh0, ac1);
            ac0 = mfma16(Al[0][1], Bh1, ac0); ac1 = mfma16(Al[1][1], Bh1, ac1);

            unsigned int sh = bits >> (quad * 4);
            if (phase == 0) {
#pragma unroll
                for (int i = 0; i < 4; ++i) {
                    if ((sh >> i) & 1)        mx[i]     = fmaxf(mx[i], ac0[i]);
                    if ((sh >> (16 + i)) & 1) mx[4 + i] = fmaxf(mx[4 + i], ac1[i]);
                }
            } else {
#pragma unroll
                for (int i = 0; i < 4; ++i) {
                    if (((sh >> i) & 1) && ac0[i] >= tau[i]) {
                        int slot = pbase + (quad * 4 + i) * 4;
                        int pos = atomicAdd(&scnt[slot], 1);
                        if (pos < CAP) { sval[(size_t)slot * CAP + pos] = ac0[i]; sidx[(size_t)slot * CAP + pos] = a; }
                    }
                    if (((sh >> (16 + i)) & 1) && ac1[i] >= tau[4 + i]) {
                        int slot = pbase + (16 + quad * 4 + i) * 4;
                        int pos = atomicAdd(&scnt[slot], 1);
                        if (pos < CAP) { sval[(size_t)slot * CAP + pos] = ac1[i]; sidx[(size_t)slot * CAP + pos] = a; }
                    }
                }
            }
        }
        if (phase == 0) {
            int b = w * 16 + n;
#pragma unroll
            for (int i = 0; i < 4; ++i) {
                bmax[quad * 4 + i][b] = mx[i];
                bmax[16 + quad * 4 + i][b] = mx[4 + i];
            }
            __syncthreads();
            if (tid < 32) {
                float t = 0.f;
                for (int pass = 0; pass < 10; ++pass) {
                    float best = NEG_INF; int bj = 0;
                    for (int j = 0; j < 64; ++j) {
                        float v = bmax[tid][j];
                        if (v > best) { best = v; bj = j; }
                    }
                    bmax[tid][bj] = NEG_INF;
                    t = best;
                }
                taus[tid] = t;
            }
            __syncthreads();
#pragma unroll
            for (int i = 0; i < 4; ++i) {
                tau[i] = taus[quad * 4 + i];
                tau[4 + i] = taus[16 + quad * 4 + i];
            }
        }
    }
}

// ---------------------------------------------------------------- K4: merge survivors + sigmoid + softmax + threshold
__global__ __launch_bounds__(256) void topk_finalize(
    const int* __restrict__ scnt, const float* __restrict__ sval, const int* __restrict__ sidx,
    float* __restrict__ sel_w, int* __restrict__ sel_i) {
    int p = blockIdx.x * 256 + threadIdx.x;
    if (p >= NH * N_RNA) return;
    float mv[10]; int mi[10];
#pragma unroll
    for (int s = 0; s < 10; ++s) { mv[s] = NEG_INF; mi[s] = 0; }
    float mn = NEG_INF; int ms = 0;
    for (int q = 0; q < 4; ++q) {
        int slot = p * 4 + q;
        int c = scnt[slot]; if (c > CAP) c = CAP;
        for (int j = 0; j < c; ++j) {
            float v = sval[(size_t)slot * CAP + j];
            if (v > mn) topk_insert(mv, mi, mn, ms, v, sidx[(size_t)slot * CAP + j]);
        }
    }
    float sg[10]; float es[10]; float sum = 0.f;
#pragma unroll
    for (int s = 0; s < 10; ++s) {
        sg[s] = 1.0f / (1.0f + expf(-mv[s]));
        es[s] = expf(sg[s]);
        sum += es[s];
    }
    float inv = 1.0f / sum;
    int base = p * 16;
#pragma unroll
    for (int s = 0; s < 10; ++s) {
        float w = es[s] * inv;
        if (!(sg[s] > 0.8f)) w = 0.f;
        sel_w[base + s] = w;
        sel_i[base + s] = mi[s];
    }
}

// ---------------------------------------------------------------- K5a: rna_agg gather
__global__ __launch_bounds__(256) void rna_gather(
    const float* __restrict__ sel_w, const int* __restrict__ sel_i,
    const float* __restrict__ v_a, float* __restrict__ rna_agg) {
    int tid = threadIdx.x;
    int r = blockIdx.x * 64 + (tid >> 2);
    int cq = tid & 3; int c0 = cq * 32; int h = cq >> 1;
    int base = (h * N_RNA + r) * 16;
    float4 acc[8];
#pragma unroll
    for (int j = 0; j < 8; ++j) acc[j] = make_float4(0.f, 0.f, 0.f, 0.f);
    for (int i = 0; i < TOPK; ++i) {
        float w = sel_w[base + i];
        int idx = sel_i[base + i];
        const float4* vp = (const float4*)(v_a + (size_t)idx * HID + c0);
#pragma unroll
        for (int j = 0; j < 8; ++j) {
            float4 v = vp[j];
            acc[j].x += w * v.x; acc[j].y += w * v.y; acc[j].z += w * v.z; acc[j].w += w * v.w;
        }
    }
    float4* op = (float4*)(rna_agg + (size_t)r * HID + c0);
#pragma unroll
    for (int j = 0; j < 8; ++j) op[j] = acc[j];
}

// ---------------------------------------------------------------- K5b: atac_agg scatter (atomics)
__global__ __launch_bounds__(256) void atac_scatter(
    const float* __restrict__ sel_w, const int* __restrict__ sel_i,
    const float* __restrict__ v_r, float* __restrict__ atac_agg) {
    int wid = threadIdx.x >> 6, lane = threadIdx.x & 63;
    int p = blockIdx.x * 4 + wid;
    int h = p >> 12; int r = p & 4095;
    float v = v_r[(size_t)r * HID + h * 64 + lane];
    int base = p * 16;
    for (int i = 0; i < TOPK; ++i) {
        float w = sel_w[base + i];
        if (w != 0.f) {
            int idx = sel_i[base + i];
            atomicAdd(&atac_agg[(size_t)idx * HID + h * 64 + lane], w * v);
        }
    }
}

// ---------------------------------------------------------------- K6: C = A@W1 + X@W2 + bias
__global__ __launch_bounds__(256) void out_gemm(
    const float* __restrict__ A, const float* __restrict__ X,
    const float* __restrict__ W1, const float* __restrict__ W2,
    const float* __restrict__ bias, float* __restrict__ C, int M) {
    int r = blockIdx.x * 8 + (threadIdx.x >> 5);
    int cg = threadIdx.x & 31; int c0 = cg * 4;
    float4 acc = *(const float4*)&bias[c0];
    const float* a = A + (size_t)r * HID;
#pragma unroll 4
    for (int k = 0; k < 128; ++k) {
        float av = a[k];
        float4 w = *(const float4*)&W1[(size_t)k * HID + c0];
        acc.x += av * w.x; acc.y += av * w.y; acc.z += av * w.z; acc.w += av * w.w;
    }
    const float* x = X + (size_t)r * IN_C;
#pragma unroll 4
    for (int k = 0; k < 256; ++k) {
        float xv = x[k];
        float4 w = *(const float4*)&W2[(size_t)k * HID + c0];
        acc.x += xv * w.x; acc.y += xv * w.y; acc.z += xv * w.z; acc.w += xv * w.w;
    }
    *(float4*)&C[(size_t)r * HID + c0] = acc;
}

// ---------------------------------------------------------------- launch
extern "C" void kernel_launch(void* const* d_in, const int* in_sizes, int n_in,
                              void* d_out, int out_size, void* d_ws, size_t ws_size,
                              hipStream_t stream) {
    const float* x_rna = (const float*)d_in[0];
    const float* x_atac = (const float*)d_in[1];
    const float* mask = (const float*)d_in[2];
    const float* Wq = (const float*)d_in[3];  const float* bq = (const float*)d_in[4];
    const float* Wk = (const float*)d_in[5];  const float* bk = (const float*)d_in[6];
    const float* Wvr = (const float*)d_in[7]; const float* bvr = (const float*)d_in[8];
    const float* Wva = (const float*)d_in[9]; const float* bva = (const float*)d_in[10];
    const float* Wor = (const float*)d_in[11]; const float* bor = (const float*)d_in[12];
    const float* Woa = (const float*)d_in[13]; const float* boa = (const float*)d_in[14];
    const float* Wsr = (const float*)d_in[15]; const float* bsr = (const float*)d_in[16];
    const float* Wsa = (const float*)d_in[17]; const float* bsa = (const float*)d_in[18];
    const float* Wdr = (const float*)d_in[19]; const float* bdr = (const float*)d_in[20];
    const float* Wda = (const float*)d_in[21]; const float* bda = (const float*)d_in[22];

    float* out_r = (float*)d_out;
    float* out_a = out_r + N_RNA * HID;

    float* ws = (float*)d_ws;
    unsigned short* qhi = (unsigned short*)ws;          // 4096x128 ushort
    unsigned short* qlo = qhi + 524288;
    unsigned short* khi = qlo + 524288;                 // 8192x128 ushort
    unsigned short* klo = khi + 1048576;
    // above = 3145728 ushorts = 1572864 floats
    unsigned int* bitsT = (unsigned int*)(ws + 1572864);  // 8192x128 uint
    float* v_r = ws + 1572864 + 1048576;                // 4096x128
    float* v_a = v_r + 524288;                          // 8192x128
    float* Wr1 = v_a + 1048576;                         // 128x128
    float* Wr2 = Wr1 + 16384;                           // 256x128
    float* brf = Wr2 + 32768;                           // 128
    float* Wa1 = brf + 128;                             // 128x128
    float* Wa2 = Wa1 + 16384;                           // 256x128
    float* baf = Wa2 + 32768;                           // 128
    int* scnt = (int*)(baf + 128);                      // 8192*4 ints
    float* sval = (float*)scnt + 32768;                 // 8192*4*32
    int* sidx = (int*)(sval + 1048576);                 // 8192*4*32
    float* sel_w = (float*)sidx + 1048576;              // 8192*16
    int* sel_i = (int*)(sel_w + 131072);                // 8192*16
    float* rna_agg = (float*)sel_i + 131072;            // 4096x128
    float* atac_agg = rna_agg + 524288;                 // 8192x128

    hipLaunchKernelGGL(fuse_weights, dim3(386), dim3(256), 0, stream,
                       Wor, bor, Woa, boa, Wsr, bsr, Wsa, bsa, Wdr, bdr, Wda, bda,
                       Wr1, Wr2, brf, Wa1, Wa2, baf);
    hipLaunchKernelGGL(mask_bits, dim3(128, 8), dim3(256), 0, stream, mask, bitsT);
    hipLaunchKernelGGL(proj_gemm, dim3(128, 4), dim3(256), 0, stream,
                       x_rna, x_atac, Wq, bq, Wk, bk, Wvr, bvr, Wva, bva,
                       qhi, qlo, khi, klo, v_r, v_a);
    hipLaunchKernelGGL(zero_buf, dim3(1024), dim3(256), 0, stream, atac_agg);
    hipLaunchKernelGGL(zero_buf, dim3(32), dim3(256), 0, stream, (float*)scnt);
    hipLaunchKernelGGL(attn_twophase, dim3(8, 128), dim3(256), 0, stream,
                       qhi, qlo, khi, klo, bitsT, scnt, sval, sidx);
    hipLaunchKernelGGL(topk_finalize, dim3(32), dim3(256), 0, stream,
                       scnt, sval, sidx, sel_w, sel_i);
    hipLaunchKernelGGL(rna_gather, dim3(64), dim3(256), 0, stream, sel_w, sel_i, v_a, rna_agg);
    hipLaunchKernelGGL(atac_scatter, dim3(2048), dim3(256), 0, stream, sel_w, sel_i, v_r, atac_agg);
    hipLaunchKernelGGL(out_gemm, dim3(512), dim3(256), 0, stream,
                       rna_agg, x_rna, Wr1, Wr2, brf, out_r, N_RNA);
    hipLaunchKernelGGL(out_gemm, dim3(1024), dim3(256), 0, stream,
                       atac_agg, x_atac, Wa1, Wa2, baf, out_a, N_ATAC);
}

// Round 3
// 589.262 us; speedup vs baseline: 1.2669x; 1.0978x over previous
//
#include <hip/hip_runtime.h>
#include <math.h>

#define N_RNA 4096
#define N_ATAC 8192
#define IN_C 256
#define HID 128
#define NH 2
#define TOPK 10
#define CAP 32
#define NEG_INF -3.402823466e38f

typedef __attribute__((ext_vector_type(8))) short bf16x8;
typedef __attribute__((ext_vector_type(4))) float f32x4;

static __device__ __forceinline__ f32x4 mfma16(bf16x8 a, bf16x8 b, f32x4 c) {
    return __builtin_amdgcn_mfma_f32_16x16x32_bf16(a, b, c, 0, 0, 0);
}

static __device__ __forceinline__ unsigned short f2bf(float f) {
    unsigned int u = __float_as_uint(f);
    unsigned int r = (u + 0x7fffu + ((u >> 16) & 1u)) >> 16;   // RNE
    return (unsigned short)r;
}
static __device__ __forceinline__ float bf2f(unsigned short h) {
    return __uint_as_float(((unsigned int)h) << 16);
}

// ---------------------------------------------------------------- top-k insert
__device__ __forceinline__ void topk_insert(float (&tv)[10], int (&ti)[10],
                                            float &mn, int &ms, float lv, int a) {
#pragma unroll
    for (int s = 0; s < 10; ++s) {
        if (s == ms) { tv[s] = lv; ti[s] = a; }
    }
    mn = tv[0]; ms = 0;
#pragma unroll
    for (int s = 1; s < 10; ++s) {
        if (tv[s] < mn) { mn = tv[s]; ms = s; }
    }
}

// ---------------------------------------------------------------- K0: prep (mask bits + zero bufs + fused weights)
// blocks [0,1024): mask->bitsT.  [1024,2048): zero atac_agg.  [2048,2080): zero scnt.
// [2080,2466): fuse weights.
__global__ __launch_bounds__(256) void prep(
    const float* __restrict__ mask, unsigned int* __restrict__ bitsT,
    float* __restrict__ atac_agg, int* __restrict__ scnt,
    const float* __restrict__ Wor, const float* __restrict__ bor,
    const float* __restrict__ Woa, const float* __restrict__ boa,
    const float* __restrict__ Wsr, const float* __restrict__ bsr,
    const float* __restrict__ Wsa, const float* __restrict__ bsa,
    const float* __restrict__ Wdr, const float* __restrict__ bdr,
    const float* __restrict__ Wda, const float* __restrict__ bda,
    float* __restrict__ Wr1, float* __restrict__ Wr2, float* __restrict__ br,
    float* __restrict__ Wa1, float* __restrict__ Wa2, float* __restrict__ ba) {
    int bx = blockIdx.x;
    if (bx < 1024) {
        __shared__ unsigned int bits_s[64][16];
        int ac = bx & 127, rc = bx >> 7;
        int w = threadIdx.x >> 6, lane = threadIdx.x & 63;
        int a = ac * 64 + lane;
        int rbase = rc * 512 + w * 128;
        unsigned int acc = 0;
        for (int rr = 0; rr < 128; ++rr) {
            float m = mask[(size_t)(rbase + rr) * N_ATAC + a];
            acc |= ((m > 0.5f) ? 1u : 0u) << (rr & 31);
            if ((rr & 31) == 31) { bits_s[lane][w * 4 + (rr >> 5)] = acc; acc = 0; }
        }
        __syncthreads();
        int t = threadIdx.x;
        int al = t >> 2, dw = (t & 3) * 4;
        uint4 v = *(const uint4*)&bits_s[al][dw];
        *(uint4*)&bitsT[(size_t)(ac * 64 + al) * 128 + rc * 16 + dw] = v;
        return;
    }
    if (bx < 2048) {
        int i = (bx - 1024) * 256 + threadIdx.x;
        *(float4*)&atac_agg[(size_t)i * 4] = make_float4(0.f, 0.f, 0.f, 0.f);
        return;
    }
    if (bx < 2080) {
        int i = (bx - 2048) * 256 + threadIdx.x;
        *(int4*)&scnt[(size_t)i * 4] = make_int4(0, 0, 0, 0);
        return;
    }
    int f = (bx - 2080) * 256 + threadIdx.x;
    if (f < 16384) {
        int i = f >> 7, j = f & 127; float s = 0.f;
        for (int t = 0; t < 128; ++t) s += Wor[i * 128 + t] * Wdr[t * 128 + j];
        Wr1[f] = s;
    } else if (f < 49152) {
        int e = f - 16384; int i = e >> 7, j = e & 127; float s = 0.f;
        for (int t = 0; t < 128; ++t) s += Wsr[i * 128 + t] * Wdr[(128 + t) * 128 + j];
        Wr2[e] = s;
    } else if (f < 65536) {
        int e = f - 49152; int i = e >> 7, j = e & 127; float s = 0.f;
        for (int t = 0; t < 128; ++t) s += Woa[i * 128 + t] * Wda[t * 128 + j];
        Wa1[e] = s;
    } else if (f < 98304) {
        int e = f - 65536; int i = e >> 7, j = e & 127; float s = 0.f;
        for (int t = 0; t < 128; ++t) s += Wsa[i * 128 + t] * Wda[(128 + t) * 128 + j];
        Wa2[e] = s;
    } else if (f < 98432) {
        int j = f - 98304; float s = bdr[j];
        for (int t = 0; t < 128; ++t) s += bor[t] * Wdr[t * 128 + j] + bsr[t] * Wdr[(128 + t) * 128 + j];
        br[j] = s;
    } else if (f < 98560) {
        int j = f - 98432; float s = bda[j];
        for (int t = 0; t < 128; ++t) s += boa[t] * Wda[t * 128 + j] + bsa[t] * Wda[(128 + t) * 128 + j];
        ba[j] = s;
    }
}

// ---------------------------------------------------------------- K1: projections
// cfg 0: q -> bf16 hi/lo planes, 1: v_r (f32), 2: k -> bf16 hi/lo, 3: v_a (f32)
__global__ __launch_bounds__(256) void proj_gemm(
    const float* __restrict__ x_rna, const float* __restrict__ x_atac,
    const float* __restrict__ Wq, const float* __restrict__ bq,
    const float* __restrict__ Wk, const float* __restrict__ bk,
    const float* __restrict__ Wvr, const float* __restrict__ bvr,
    const float* __restrict__ Wva, const float* __restrict__ bva,
    unsigned short* __restrict__ qhi, unsigned short* __restrict__ qlo,
    unsigned short* __restrict__ khi, unsigned short* __restrict__ klo,
    float* __restrict__ v_r, float* __restrict__ v_a) {
    int cfg = blockIdx.y;
    const float *X, *W, *B; int M;
    unsigned short *hi = 0, *lo = 0; float* C = 0;
    if (cfg == 0)      { X = x_rna;  W = Wq;  B = bq;  M = N_RNA;  hi = qhi; lo = qlo; }
    else if (cfg == 1) { X = x_rna;  W = Wvr; B = bvr; M = N_RNA;  C = v_r; }
    else if (cfg == 2) { X = x_atac; W = Wk;  B = bk;  M = N_ATAC; hi = khi; lo = klo; }
    else               { X = x_atac; W = Wva; B = bva; M = N_ATAC; C = v_a; }
    int r0 = blockIdx.x * 64;
    if (r0 >= M) return;

    __shared__ __align__(16) float x_s[64][33];
    __shared__ __align__(16) float w_s[32][128];
    int tid = threadIdx.x;
    int rg = tid >> 4, cg = tid & 15;

    float acc[4][8];
#pragma unroll
    for (int i = 0; i < 4; ++i)
#pragma unroll
        for (int j = 0; j < 8; ++j) acc[i][j] = 0.f;

    for (int k0 = 0; k0 < IN_C; k0 += 32) {
        __syncthreads();
        for (int i4 = tid; i4 < 512; i4 += 256) {
            int rr = i4 >> 3, kq = i4 & 7;
            float4 v = *(const float4*)&X[(size_t)(r0 + rr) * IN_C + k0 + kq * 4];
            x_s[rr][kq * 4 + 0] = v.x; x_s[rr][kq * 4 + 1] = v.y;
            x_s[rr][kq * 4 + 2] = v.z; x_s[rr][kq * 4 + 3] = v.w;
        }
        for (int i4 = tid; i4 < 1024; i4 += 256) {
            int kk = i4 >> 5, cq = i4 & 31;
            float4 v = *(const float4*)&W[(size_t)(k0 + kk) * HID + cq * 4];
            *(float4*)&w_s[kk][cq * 4] = v;
        }
        __syncthreads();
#pragma unroll 8
        for (int kk = 0; kk < 32; ++kk) {
            float x0 = x_s[rg * 4 + 0][kk], x1 = x_s[rg * 4 + 1][kk];
            float x2 = x_s[rg * 4 + 2][kk], x3 = x_s[rg * 4 + 3][kk];
            float4 wa = *(const float4*)&w_s[kk][cg * 4];
            float4 wb = *(const float4*)&w_s[kk][64 + cg * 4];
            acc[0][0] += x0 * wa.x; acc[0][1] += x0 * wa.y; acc[0][2] += x0 * wa.z; acc[0][3] += x0 * wa.w;
            acc[0][4] += x0 * wb.x; acc[0][5] += x0 * wb.y; acc[0][6] += x0 * wb.z; acc[0][7] += x0 * wb.w;
            acc[1][0] += x1 * wa.x; acc[1][1] += x1 * wa.y; acc[1][2] += x1 * wa.z; acc[1][3] += x1 * wa.w;
            acc[1][4] += x1 * wb.x; acc[1][5] += x1 * wb.y; acc[1][6] += x1 * wb.z; acc[1][7] += x1 * wb.w;
            acc[2][0] += x2 * wa.x; acc[2][1] += x2 * wa.y; acc[2][2] += x2 * wa.z; acc[2][3] += x2 * wa.w;
            acc[2][4] += x2 * wb.x; acc[2][5] += x2 * wb.y; acc[2][6] += x2 * wb.z; acc[2][7] += x2 * wb.w;
            acc[3][0] += x3 * wa.x; acc[3][1] += x3 * wa.y; acc[3][2] += x3 * wa.z; acc[3][3] += x3 * wa.w;
            acc[3][4] += x3 * wb.x; acc[3][5] += x3 * wb.y; acc[3][6] += x3 * wb.z; acc[3][7] += x3 * wb.w;
        }
    }
    float bv[8];
#pragma unroll
    for (int j = 0; j < 8; ++j) {
        int c = (j < 4) ? (cg * 4 + j) : (64 + cg * 4 + (j - 4));
        bv[j] = B[c];
    }
    if (hi) {
#pragma unroll
        for (int i = 0; i < 4; ++i) {
            int r = r0 + rg * 4 + i;
            ushort4 h0, l0, h1, l1;
            float va[8];
#pragma unroll
            for (int j = 0; j < 8; ++j) va[j] = acc[i][j] + bv[j];
            h0.x = f2bf(va[0]); h0.y = f2bf(va[1]); h0.z = f2bf(va[2]); h0.w = f2bf(va[3]);
            h1.x = f2bf(va[4]); h1.y = f2bf(va[5]); h1.z = f2bf(va[6]); h1.w = f2bf(va[7]);
            l0.x = f2bf(va[0] - bf2f(h0.x)); l0.y = f2bf(va[1] - bf2f(h0.y));
            l0.z = f2bf(va[2] - bf2f(h0.z)); l0.w = f2bf(va[3] - bf2f(h0.w));
            l1.x = f2bf(va[4] - bf2f(h1.x)); l1.y = f2bf(va[5] - bf2f(h1.y));
            l1.z = f2bf(va[6] - bf2f(h1.z)); l1.w = f2bf(va[7] - bf2f(h1.w));
            *(ushort4*)&hi[(size_t)r * 128 + cg * 4] = h0;
            *(ushort4*)&hi[(size_t)r * 128 + 64 + cg * 4] = h1;
            *(ushort4*)&lo[(size_t)r * 128 + cg * 4] = l0;
            *(ushort4*)&lo[(size_t)r * 128 + 64 + cg * 4] = l1;
        }
    } else {
#pragma unroll
        for (int i = 0; i < 4; ++i) {
            int r = r0 + rg * 4 + i;
            float4 oa = make_float4(acc[i][0] + bv[0], acc[i][1] + bv[1], acc[i][2] + bv[2], acc[i][3] + bv[3]);
            float4 ob = make_float4(acc[i][4] + bv[4], acc[i][5] + bv[5], acc[i][6] + bv[6], acc[i][7] + bv[7]);
            *(float4*)&C[(size_t)r * HID + cg * 4] = oa;
            *(float4*)&C[(size_t)r * HID + 64 + cg * 4] = ob;
        }
    }
}

// ---------------------------------------------------------------- K2: two-phase MFMA attention top-k
// grid (8 = h*4+quarter, 128 rtiles), block 256 (4 waves).
// Phase A: per-(row, bucket) masked max -> tau_row = 10th largest of 64 bucket maxes.
// Phase B: rescan, append survivors to LDS lists (block owns its slots), bulk write.
__global__ __launch_bounds__(256) void attn_twophase(
    const unsigned short* __restrict__ qhi, const unsigned short* __restrict__ qlo,
    const unsigned short* __restrict__ khi, const unsigned short* __restrict__ klo,
    const unsigned int* __restrict__ bitsT,
    int* __restrict__ scnt, float* __restrict__ sval, int* __restrict__ sidx) {
    int hq = blockIdx.x; int h = hq >> 2, qtr = hq & 3;
    int rt = blockIdx.y; int r0 = rt * 32;
    int tid = threadIdx.x;
    int w = tid >> 6, lane = tid & 63;
    int n = lane & 15, quad = lane >> 4;
    int aw0 = qtr * 2048 + w * 512;
    int pbase = (h * N_RNA + r0) * 4 + qtr;

    __shared__ float bmax[32][65];
    __shared__ float taus[32];
    __shared__ int   lcnt[32];
    __shared__ float lval[32][CAP];
    __shared__ int   lidx[32][CAP];

    // Preload A-frags (reused for the whole a-scan, both phases)
    bf16x8 Ah[2][2], Al[2][2];
#pragma unroll
    for (int mt = 0; mt < 2; ++mt)
#pragma unroll
        for (int c = 0; c < 2; ++c) {
            size_t off = (size_t)(r0 + mt * 16 + n) * 128 + h * 64 + c * 32 + quad * 8;
            Ah[mt][c] = *(const bf16x8*)(qhi + off);
            Al[mt][c] = *(const bf16x8*)(qlo + off);
        }

    if (tid < 32) lcnt[tid] = 0;

    float mx[8];
#pragma unroll
    for (int i = 0; i < 8; ++i) mx[i] = 0.f;

    // ---------------- phase A: bucket maxes ----------------
#pragma unroll 2
    for (int sub = 0; sub < 32; ++sub) {
        int a = aw0 + sub * 16 + n;
        size_t koff = (size_t)a * 128 + h * 64 + quad * 8;
        bf16x8 Bh0 = *(const bf16x8*)(khi + koff);
        bf16x8 Bh1 = *(const bf16x8*)(khi + koff + 32);
        bf16x8 Bl0 = *(const bf16x8*)(klo + koff);
        bf16x8 Bl1 = *(const bf16x8*)(klo + koff + 32);
        unsigned int bits = bitsT[(size_t)a * 128 + rt];

        f32x4 ac0 = {0.f, 0.f, 0.f, 0.f}, ac1 = {0.f, 0.f, 0.f, 0.f};
        ac0 = mfma16(Ah[0][0], Bh0, ac0); ac1 = mfma16(Ah[1][0], Bh0, ac1);
        ac0 = mfma16(Ah[0][1], Bh1, ac0); ac1 = mfma16(Ah[1][1], Bh1, ac1);
        ac0 = mfma16(Ah[0][0], Bl0, ac0); ac1 = mfma16(Ah[1][0], Bl0, ac1);
        ac0 = mfma16(Ah[0][1], Bl1, ac0); ac1 = mfma16(Ah[1][1], Bl1, ac1);
        ac0 = mfma16(Al[0][0], Bh0, ac0); ac1 = mfma16(Al[1][0], Bh0, ac1);
        ac0 = mfma16(Al[0][1], Bh1, ac0); ac1 = mfma16(Al[1][1], Bh1, ac1);

        unsigned int sh = bits >> (quad * 4);
#pragma unroll
        for (int i = 0; i < 4; ++i) {
            if ((sh >> i) & 1)        mx[i]     = fmaxf(mx[i], ac0[i]);
            if ((sh >> (16 + i)) & 1) mx[4 + i] = fmaxf(mx[4 + i], ac1[i]);
        }
    }

    {
        int b = w * 16 + n;
#pragma unroll
        for (int i = 0; i < 4; ++i) {
            bmax[quad * 4 + i][b] = mx[i];
            bmax[16 + quad * 4 + i][b] = mx[4 + i];
        }
    }
    __syncthreads();
    if (tid < 32) {
        float t = 0.f;
        for (int pass = 0; pass < 10; ++pass) {
            float best = NEG_INF; int bj = 0;
            for (int j = 0; j < 64; ++j) {
                float v = bmax[tid][j];
                if (v > best) { best = v; bj = j; }
            }
            bmax[tid][bj] = NEG_INF;
            t = best;
        }
        taus[tid] = t;
    }
    __syncthreads();

    float tau[8];
#pragma unroll
    for (int i = 0; i < 4; ++i) {
        tau[i] = taus[quad * 4 + i];
        tau[4 + i] = taus[16 + quad * 4 + i];
    }

    // ---------------- phase B: collect survivors into LDS ----------------
#pragma unroll 2
    for (int sub = 0; sub < 32; ++sub) {
        int a = aw0 + sub * 16 + n;
        size_t koff = (size_t)a * 128 + h * 64 + quad * 8;
        bf16x8 Bh0 = *(const bf16x8*)(khi + koff);
        bf16x8 Bh1 = *(const bf16x8*)(khi + koff + 32);
        bf16x8 Bl0 = *(const bf16x8*)(klo + koff);
        bf16x8 Bl1 = *(const bf16x8*)(klo + koff + 32);
        unsigned int bits = bitsT[(size_t)a * 128 + rt];

        f32x4 ac0 = {0.f, 0.f, 0.f, 0.f}, ac1 = {0.f, 0.f, 0.f, 0.f};
        ac0 = mfma16(Ah[0][0], Bh0, ac0); ac1 = mfma16(Ah[1][0], Bh0, ac1);
        ac0 = mfma16(Ah[0][1], Bh1, ac0); ac1 = mfma16(Ah[1][1], Bh1, ac1);
        ac0 = mfma16(Ah[0][0], Bl0, ac0); ac1 = mfma16(Ah[1][0], Bl0, ac1);
        ac0 = mfma16(Ah[0][1], Bl1, ac0); ac1 = mfma16(Ah[1][1], Bl1, ac1);
        ac0 = mfma16(Al[0][0], Bh0, ac0); ac1 = mfma16(Al[1][0], Bh0, ac1);
        ac0 = mfma16(Al[0][1], Bh1, ac0); ac1 = mfma16(Al[1][1], Bh1, ac1);

        unsigned int sh = bits >> (quad * 4);
#pragma unroll
        for (int i = 0; i < 4; ++i) {
            if (((sh >> i) & 1) && ac0[i] >= tau[i]) {
                int row = quad * 4 + i;
                int pos = atomicAdd(&lcnt[row], 1);
                if (pos < CAP) { lval[row][pos] = ac0[i]; lidx[row][pos] = a; }
            }
            if (((sh >> (16 + i)) & 1) && ac1[i] >= tau[4 + i]) {
                int row = 16 + quad * 4 + i;
                int pos = atomicAdd(&lcnt[row], 1);
                if (pos < CAP) { lval[row][pos] = ac1[i]; lidx[row][pos] = a; }
            }
        }
    }
    __syncthreads();

    // bulk write: block exclusively owns slots (pbase + row*4)
    if (tid < 32) {
        int c = lcnt[tid]; if (c > CAP) c = CAP;
        scnt[pbase + tid * 4] = c;
    }
    {
        int row = tid >> 3, j0 = tid & 7;
        int c = lcnt[row]; if (c > CAP) c = CAP;
        int slot = pbase + row * 4;
        for (int j = j0; j < c; j += 8) {
            sval[(size_t)slot * CAP + j] = lval[row][j];
            sidx[(size_t)slot * CAP + j] = lidx[row][j];
        }
    }
}

// ---------------------------------------------------------------- K3: merge survivors + sigmoid + softmax + threshold
__global__ __launch_bounds__(256) void topk_finalize(
    const int* __restrict__ scnt, const float* __restrict__ sval, const int* __restrict__ sidx,
    float* __restrict__ sel_w, int* __restrict__ sel_i) {
    int p = blockIdx.x * 256 + threadIdx.x;
    if (p >= NH * N_RNA) return;
    float mv[10]; int mi[10];
#pragma unroll
    for (int s = 0; s < 10; ++s) { mv[s] = NEG_INF; mi[s] = 0; }
    float mn = NEG_INF; int ms = 0;
    for (int q = 0; q < 4; ++q) {
        int slot = p * 4 + q;
        int c = scnt[slot]; if (c > CAP) c = CAP;
        for (int j = 0; j < c; ++j) {
            float v = sval[(size_t)slot * CAP + j];
            if (v > mn) topk_insert(mv, mi, mn, ms, v, sidx[(size_t)slot * CAP + j]);
        }
    }
    float sg[10]; float es[10]; float sum = 0.f;
#pragma unroll
    for (int s = 0; s < 10; ++s) {
        sg[s] = 1.0f / (1.0f + expf(-mv[s]));
        es[s] = expf(sg[s]);
        sum += es[s];
    }
    float inv = 1.0f / sum;
    int base = p * 16;
#pragma unroll
    for (int s = 0; s < 10; ++s) {
        float w = es[s] * inv;
        if (!(sg[s] > 0.8f)) w = 0.f;
        sel_w[base + s] = w;
        sel_i[base + s] = mi[s];
    }
}

// ---------------------------------------------------------------- K4: aggregations (gather + scatter)
// blocks [0,256): rna gather (1 thread per (row, 8-col group)).
// blocks [256,2304): atac scatter.
__global__ __launch_bounds__(256) void agg(
    const float* __restrict__ sel_w, const int* __restrict__ sel_i,
    const float* __restrict__ v_a, const float* __restrict__ v_r,
    float* __restrict__ rna_agg, float* __restrict__ atac_agg) {
    int bx = blockIdx.x;
    if (bx < 256) {
        int gid = bx * 256 + threadIdx.x;
        int r = gid >> 4, g = gid & 15;
        int c0 = g * 8; int h = g >> 3;
        int base = (h * N_RNA + r) * 16;
        float4 a0 = make_float4(0.f, 0.f, 0.f, 0.f);
        float4 a1 = make_float4(0.f, 0.f, 0.f, 0.f);
        for (int i = 0; i < TOPK; ++i) {
            float w = sel_w[base + i];
            int idx = sel_i[base + i];
            const float4* vp = (const float4*)(v_a + (size_t)idx * HID + c0);
            float4 v0 = vp[0], v1 = vp[1];
            a0.x += w * v0.x; a0.y += w * v0.y; a0.z += w * v0.z; a0.w += w * v0.w;
            a1.x += w * v1.x; a1.y += w * v1.y; a1.z += w * v1.z; a1.w += w * v1.w;
        }
        float4* op = (float4*)(rna_agg + (size_t)r * HID + c0);
        op[0] = a0; op[1] = a1;
        return;
    }
    int wid = threadIdx.x >> 6, lane = threadIdx.x & 63;
    int p = (bx - 256) * 4 + wid;
    int h = p >> 12; int r = p & 4095;
    float v = v_r[(size_t)r * HID + h * 64 + lane];
    int base = p * 16;
    for (int i = 0; i < TOPK; ++i) {
        float w = sel_w[base + i];
        if (w != 0.f) {
            int idx = sel_i[base + i];
            atomicAdd(&atac_agg[(size_t)idx * HID + h * 64 + lane], w * v);
        }
    }
}

// ---------------------------------------------------------------- K5: C = A@W1 + X@W2 + bias (both outputs)
__global__ __launch_bounds__(256) void out_gemm(
    const float* __restrict__ rna_agg, const float* __restrict__ x_rna,
    const float* __restrict__ Wr1, const float* __restrict__ Wr2, const float* __restrict__ brf,
    const float* __restrict__ atac_agg, const float* __restrict__ x_atac,
    const float* __restrict__ Wa1, const float* __restrict__ Wa2, const float* __restrict__ baf,
    float* __restrict__ out_r, float* __restrict__ out_a) {
    int bx = blockIdx.x;
    const float *A, *X, *W1, *W2, *bias; float* C;
    int rb;
    if (bx < 512) { A = rna_agg; X = x_rna; W1 = Wr1; W2 = Wr2; bias = brf; C = out_r; rb = bx; }
    else { A = atac_agg; X = x_atac; W1 = Wa1; W2 = Wa2; bias = baf; C = out_a; rb = bx - 512; }
    int r = rb * 8 + (threadIdx.x >> 5);
    int cg = threadIdx.x & 31; int c0 = cg * 4;
    float4 acc = *(const float4*)&bias[c0];
    const float* a = A + (size_t)r * HID;
#pragma unroll 4
    for (int k = 0; k < 128; ++k) {
        float av = a[k];
        float4 w = *(const float4*)&W1[(size_t)k * HID + c0];
        acc.x += av * w.x; acc.y += av * w.y; acc.z += av * w.z; acc.w += av * w.w;
    }
    const float* x = X + (size_t)r * IN_C;
#pragma unroll 4
    for (int k = 0; k < 256; ++k) {
        float xv = x[k];
        float4 w = *(const float4*)&W2[(size_t)k * HID + c0];
        acc.x += xv * w.x; acc.y += xv * w.y; acc.z += xv * w.z; acc.w += xv * w.w;
    }
    *(float4*)&C[(size_t)r * HID + c0] = acc;
}

// ---------------------------------------------------------------- launch
extern "C" void kernel_launch(void* const* d_in, const int* in_sizes, int n_in,
                              void* d_out, int out_size, void* d_ws, size_t ws_size,
                              hipStream_t stream) {
    const float* x_rna = (const float*)d_in[0];
    const float* x_atac = (const float*)d_in[1];
    const float* mask = (const float*)d_in[2];
    const float* Wq = (const float*)d_in[3];  const float* bq = (const float*)d_in[4];
    const float* Wk = (const float*)d_in[5];  const float* bk = (const float*)d_in[6];
    const float* Wvr = (const float*)d_in[7]; const float* bvr = (const float*)d_in[8];
    const float* Wva = (const float*)d_in[9]; const float* bva = (const float*)d_in[10];
    const float* Wor = (const float*)d_in[11]; const float* bor = (const float*)d_in[12];
    const float* Woa = (const float*)d_in[13]; const float* boa = (const float*)d_in[14];
    const float* Wsr = (const float*)d_in[15]; const float* bsr = (const float*)d_in[16];
    const float* Wsa = (const float*)d_in[17]; const float* bsa = (const float*)d_in[18];
    const float* Wdr = (const float*)d_in[19]; const float* bdr = (const float*)d_in[20];
    const float* Wda = (const float*)d_in[21]; const float* bda = (const float*)d_in[22];

    float* out_r = (float*)d_out;
    float* out_a = out_r + N_RNA * HID;

    float* ws = (float*)d_ws;
    unsigned short* qhi = (unsigned short*)ws;          // 4096x128 ushort
    unsigned short* qlo = qhi + 524288;
    unsigned short* khi = qlo + 524288;                 // 8192x128 ushort
    unsigned short* klo = khi + 1048576;
    unsigned int* bitsT = (unsigned int*)(ws + 1572864);  // 8192x128 uint
    float* v_r = ws + 1572864 + 1048576;                // 4096x128
    float* v_a = v_r + 524288;                          // 8192x128
    float* Wr1 = v_a + 1048576;                         // 128x128
    float* Wr2 = Wr1 + 16384;                           // 256x128
    float* brf = Wr2 + 32768;                           // 128
    float* Wa1 = brf + 128;                             // 128x128
    float* Wa2 = Wa1 + 16384;                           // 256x128
    float* baf = Wa2 + 32768;                           // 128
    int* scnt = (int*)(baf + 128);                      // 8192*4 ints
    float* sval = (float*)scnt + 32768;                 // 8192*4*32
    int* sidx = (int*)(sval + 1048576);                 // 8192*4*32
    float* sel_w = (float*)sidx + 1048576;              // 8192*16
    int* sel_i = (int*)(sel_w + 131072);                // 8192*16
    float* rna_agg = (float*)sel_i + 131072;            // 4096x128
    float* atac_agg = rna_agg + 524288;                 // 8192x128

    hipLaunchKernelGGL(prep, dim3(2466), dim3(256), 0, stream,
                       mask, bitsT, atac_agg, scnt,
                       Wor, bor, Woa, boa, Wsr, bsr, Wsa, bsa, Wdr, bdr, Wda, bda,
                       Wr1, Wr2, brf, Wa1, Wa2, baf);
    hipLaunchKernelGGL(proj_gemm, dim3(128, 4), dim3(256), 0, stream,
                       x_rna, x_atac, Wq, bq, Wk, bk, Wvr, bvr, Wva, bva,
                       qhi, qlo, khi, klo, v_r, v_a);
    hipLaunchKernelGGL(attn_twophase, dim3(8, 128), dim3(256), 0, stream,
                       qhi, qlo, khi, klo, bitsT, scnt, sval, sidx);
    hipLaunchKernelGGL(topk_finalize, dim3(32), dim3(256), 0, stream,
                       scnt, sval, sidx, sel_w, sel_i);
    hipLaunchKernelGGL(agg, dim3(2304), dim3(256), 0, stream,
                       sel_w, sel_i, v_a, v_r, rna_agg, atac_agg);
    hipLaunchKernelGGL(out_gemm, dim3(1536), dim3(256), 0, stream,
                       rna_agg, x_rna, Wr1, Wr2, brf,
                       atac_agg, x_atac, Wa1, Wa2, baf, out_r, out_a);
}

// Round 4
// 531.999 us; speedup vs baseline: 1.4032x; 1.1076x over previous
//
#include <hip/hip_runtime.h>
#include <math.h>

#define N_RNA 4096
#define N_ATAC 8192
#define IN_C 256
#define HID 128
#define NH 2
#define TOPK 10
#define CAP 64
#define TAU_EPS 0.12f
#define NEG_INF -3.402823466e38f

typedef __attribute__((ext_vector_type(8))) short bf16x8;
typedef __attribute__((ext_vector_type(4))) float f32x4;

static __device__ __forceinline__ f32x4 mfma16(bf16x8 a, bf16x8 b, f32x4 c) {
    return __builtin_amdgcn_mfma_f32_16x16x32_bf16(a, b, c, 0, 0, 0);
}

static __device__ __forceinline__ unsigned short f2bf(float f) {
    unsigned int u = __float_as_uint(f);
    unsigned int r = (u + 0x7fffu + ((u >> 16) & 1u)) >> 16;   // RNE
    return (unsigned short)r;
}
static __device__ __forceinline__ float bf2f(unsigned short h) {
    return __uint_as_float(((unsigned int)h) << 16);
}

// ---------------------------------------------------------------- top-k insert
__device__ __forceinline__ void topk_insert(float (&tv)[10], int (&ti)[10],
                                            float &mn, int &ms, float lv, int a) {
#pragma unroll
    for (int s = 0; s < 10; ++s) {
        if (s == ms) { tv[s] = lv; ti[s] = a; }
    }
    mn = tv[0]; ms = 0;
#pragma unroll
    for (int s = 1; s < 10; ++s) {
        if (tv[s] < mn) { mn = tv[s]; ms = s; }
    }
}

// ---------------------------------------------------------------- K0a: mask -> bits2[rt64][a][2]
// grid 2048: rt = bx>>5 (64 row-tiles of 64), ac = bx&31 (256-a chunks)
__global__ __launch_bounds__(256) void prep_bits(
    const float* __restrict__ mask, unsigned int* __restrict__ bits2) {
    int bx = blockIdx.x;
    int rt = bx >> 5, ac = bx & 31;
    int a = ac * 256 + threadIdx.x;
    int r0 = rt * 64;
    unsigned int w0 = 0, w1 = 0;
#pragma unroll 8
    for (int rr = 0; rr < 32; ++rr) {
        float m0 = mask[(size_t)(r0 + rr) * N_ATAC + a];
        float m1 = mask[(size_t)(r0 + 32 + rr) * N_ATAC + a];
        w0 |= ((m0 > 0.5f) ? 1u : 0u) << rr;
        w1 |= ((m1 > 0.5f) ? 1u : 0u) << rr;
    }
    *(uint2*)&bits2[((size_t)rt * N_ATAC + a) * 2] = make_uint2(w0, w1);
}

// ---------------------------------------------------------------- K0b: zeros + fused weights
// [0,1024): zero atac_agg; [1024,1040): zero scnt; [1040,1426): fuse weights
__global__ __launch_bounds__(256) void prep_misc(
    float* __restrict__ atac_agg, int* __restrict__ scnt,
    const float* __restrict__ Wor, const float* __restrict__ bor,
    const float* __restrict__ Woa, const float* __restrict__ boa,
    const float* __restrict__ Wsr, const float* __restrict__ bsr,
    const float* __restrict__ Wsa, const float* __restrict__ bsa,
    const float* __restrict__ Wdr, const float* __restrict__ bdr,
    const float* __restrict__ Wda, const float* __restrict__ bda,
    float* __restrict__ Wr1, float* __restrict__ Wr2, float* __restrict__ br,
    float* __restrict__ Wa1, float* __restrict__ Wa2, float* __restrict__ ba) {
    int bx = blockIdx.x;
    if (bx < 1024) {
        int i = bx * 256 + threadIdx.x;
        *(float4*)&atac_agg[(size_t)i * 4] = make_float4(0.f, 0.f, 0.f, 0.f);
        return;
    }
    if (bx < 1040) {
        int i = (bx - 1024) * 256 + threadIdx.x;
        *(int4*)&scnt[(size_t)i * 4] = make_int4(0, 0, 0, 0);
        return;
    }
    int f = (bx - 1040) * 256 + threadIdx.x;
    if (f < 16384) {
        int i = f >> 7, j = f & 127; float s = 0.f;
        for (int t = 0; t < 128; ++t) s += Wor[i * 128 + t] * Wdr[t * 128 + j];
        Wr1[f] = s;
    } else if (f < 49152) {
        int e = f - 16384; int i = e >> 7, j = e & 127; float s = 0.f;
        for (int t = 0; t < 128; ++t) s += Wsr[i * 128 + t] * Wdr[(128 + t) * 128 + j];
        Wr2[e] = s;
    } else if (f < 65536) {
        int e = f - 49152; int i = e >> 7, j = e & 127; float s = 0.f;
        for (int t = 0; t < 128; ++t) s += Woa[i * 128 + t] * Wda[t * 128 + j];
        Wa1[e] = s;
    } else if (f < 98304) {
        int e = f - 65536; int i = e >> 7, j = e & 127; float s = 0.f;
        for (int t = 0; t < 128; ++t) s += Wsa[i * 128 + t] * Wda[(128 + t) * 128 + j];
        Wa2[e] = s;
    } else if (f < 98432) {
        int j = f - 98304; float s = bdr[j];
        for (int t = 0; t < 128; ++t) s += bor[t] * Wdr[t * 128 + j] + bsr[t] * Wdr[(128 + t) * 128 + j];
        br[j] = s;
    } else if (f < 98560) {
        int j = f - 98432; float s = bda[j];
        for (int t = 0; t < 128; ++t) s += boa[t] * Wda[t * 128 + j] + bsa[t] * Wda[(128 + t) * 128 + j];
        ba[j] = s;
    }
}

// ---------------------------------------------------------------- K1: projections
// cfg 0: q -> bf16 hi/lo per-head rows [h][r][64]
// cfg 2: k -> bf16 hi/lo MFMA-fragment layout [h][at][kc][n][8]
// cfg 1/3: v_r / v_a fp32 rows
__global__ __launch_bounds__(256) void proj_gemm(
    const float* __restrict__ x_rna, const float* __restrict__ x_atac,
    const float* __restrict__ Wq, const float* __restrict__ bq,
    const float* __restrict__ Wk, const float* __restrict__ bk,
    const float* __restrict__ Wvr, const float* __restrict__ bvr,
    const float* __restrict__ Wva, const float* __restrict__ bva,
    unsigned short* __restrict__ qhi, unsigned short* __restrict__ qlo,
    unsigned short* __restrict__ khf_hi, unsigned short* __restrict__ khf_lo,
    float* __restrict__ v_r, float* __restrict__ v_a) {
    int cfg = blockIdx.y;
    const float *X, *W, *B; int M;
    if (cfg == 0)      { X = x_rna;  W = Wq;  B = bq;  M = N_RNA;  }
    else if (cfg == 1) { X = x_rna;  W = Wvr; B = bvr; M = N_RNA;  }
    else if (cfg == 2) { X = x_atac; W = Wk;  B = bk;  M = N_ATAC; }
    else               { X = x_atac; W = Wva; B = bva; M = N_ATAC; }
    int r0 = blockIdx.x * 64;
    if (r0 >= M) return;

    __shared__ __align__(16) float x_s[64][33];
    __shared__ __align__(16) float w_s[32][128];
    int tid = threadIdx.x;
    int rg = tid >> 4, cg = tid & 15;

    float acc[4][8];
#pragma unroll
    for (int i = 0; i < 4; ++i)
#pragma unroll
        for (int j = 0; j < 8; ++j) acc[i][j] = 0.f;

    for (int k0 = 0; k0 < IN_C; k0 += 32) {
        __syncthreads();
        for (int i4 = tid; i4 < 512; i4 += 256) {
            int rr = i4 >> 3, kq = i4 & 7;
            float4 v = *(const float4*)&X[(size_t)(r0 + rr) * IN_C + k0 + kq * 4];
            x_s[rr][kq * 4 + 0] = v.x; x_s[rr][kq * 4 + 1] = v.y;
            x_s[rr][kq * 4 + 2] = v.z; x_s[rr][kq * 4 + 3] = v.w;
        }
        for (int i4 = tid; i4 < 1024; i4 += 256) {
            int kk = i4 >> 5, cq = i4 & 31;
            float4 v = *(const float4*)&W[(size_t)(k0 + kk) * HID + cq * 4];
            *(float4*)&w_s[kk][cq * 4] = v;
        }
        __syncthreads();
#pragma unroll 8
        for (int kk = 0; kk < 32; ++kk) {
            float x0 = x_s[rg * 4 + 0][kk], x1 = x_s[rg * 4 + 1][kk];
            float x2 = x_s[rg * 4 + 2][kk], x3 = x_s[rg * 4 + 3][kk];
            float4 wa = *(const float4*)&w_s[kk][cg * 4];
            float4 wb = *(const float4*)&w_s[kk][64 + cg * 4];
            acc[0][0] += x0 * wa.x; acc[0][1] += x0 * wa.y; acc[0][2] += x0 * wa.z; acc[0][3] += x0 * wa.w;
            acc[0][4] += x0 * wb.x; acc[0][5] += x0 * wb.y; acc[0][6] += x0 * wb.z; acc[0][7] += x0 * wb.w;
            acc[1][0] += x1 * wa.x; acc[1][1] += x1 * wa.y; acc[1][2] += x1 * wa.z; acc[1][3] += x1 * wa.w;
            acc[1][4] += x1 * wb.x; acc[1][5] += x1 * wb.y; acc[1][6] += x1 * wb.z; acc[1][7] += x1 * wb.w;
            acc[2][0] += x2 * wa.x; acc[2][1] += x2 * wa.y; acc[2][2] += x2 * wa.z; acc[2][3] += x2 * wa.w;
            acc[2][4] += x2 * wb.x; acc[2][5] += x2 * wb.y; acc[2][6] += x2 * wb.z; acc[2][7] += x2 * wb.w;
            acc[3][0] += x3 * wa.x; acc[3][1] += x3 * wa.y; acc[3][2] += x3 * wa.z; acc[3][3] += x3 * wa.w;
            acc[3][4] += x3 * wb.x; acc[3][5] += x3 * wb.y; acc[3][6] += x3 * wb.z; acc[3][7] += x3 * wb.w;
        }
    }
    float bv[8];
#pragma unroll
    for (int j = 0; j < 8; ++j) {
        int c = (j < 4) ? (cg * 4 + j) : (64 + cg * 4 + (j - 4));
        bv[j] = B[c];
    }
    if (cfg == 0 || cfg == 2) {
#pragma unroll
        for (int i = 0; i < 4; ++i) {
            int r = r0 + rg * 4 + i;
            float va[8];
#pragma unroll
            for (int j = 0; j < 8; ++j) va[j] = acc[i][j] + bv[j];
            ushort4 h0, l0, h1, l1;
            h0.x = f2bf(va[0]); h0.y = f2bf(va[1]); h0.z = f2bf(va[2]); h0.w = f2bf(va[3]);
            h1.x = f2bf(va[4]); h1.y = f2bf(va[5]); h1.z = f2bf(va[6]); h1.w = f2bf(va[7]);
            l0.x = f2bf(va[0] - bf2f(h0.x)); l0.y = f2bf(va[1] - bf2f(h0.y));
            l0.z = f2bf(va[2] - bf2f(h0.z)); l0.w = f2bf(va[3] - bf2f(h0.w));
            l1.x = f2bf(va[4] - bf2f(h1.x)); l1.y = f2bf(va[5] - bf2f(h1.y));
            l1.z = f2bf(va[6] - bf2f(h1.z)); l1.w = f2bf(va[7] - bf2f(h1.w));
            if (cfg == 0) {
                // q: [h][r][64] rows
                size_t o0 = (size_t)r * 64 + cg * 4;                 // head 0
                size_t o1 = (size_t)(N_RNA + r) * 64 + cg * 4;       // head 1
                *(ushort4*)&qhi[o0] = h0; *(ushort4*)&qhi[o1] = h1;
                *(ushort4*)&qlo[o0] = l0; *(ushort4*)&qlo[o1] = l1;
            } else {
                // k fragment layout: ((h*512 + at)*8 + kc)*128 + n*8 + e
                int at = r >> 4, n = r & 15;
                int kc = cg >> 1, e = (cg & 1) * 4;
                size_t o0 = ((size_t)(at) * 8 + kc) * 128 + n * 8 + e;          // head 0
                size_t o1 = ((size_t)(512 + at) * 8 + kc) * 128 + n * 8 + e;    // head 1
                *(ushort4*)&khf_hi[o0] = h0; *(ushort4*)&khf_hi[o1] = h1;
                *(ushort4*)&khf_lo[o0] = l0; *(ushort4*)&khf_lo[o1] = l1;
            }
        }
    } else {
        float* C = (cfg == 1) ? v_r : v_a;
#pragma unroll
        for (int i = 0; i < 4; ++i) {
            int r = r0 + rg * 4 + i;
            float4 oa = make_float4(acc[i][0] + bv[0], acc[i][1] + bv[1], acc[i][2] + bv[2], acc[i][3] + bv[3]);
            float4 ob = make_float4(acc[i][4] + bv[4], acc[i][5] + bv[5], acc[i][6] + bv[6], acc[i][7] + bv[7]);
            *(float4*)&C[(size_t)r * HID + cg * 4] = oa;
            *(float4*)&C[(size_t)r * HID + 64 + cg * 4] = ob;
        }
    }
}

// ---------------------------------------------------------------- K2: two-phase MFMA attention (fragment-direct)
// grid (4 = h*2+half, 64 rtiles of 64 rows), block 256 (4 waves, 1 block/CU).
// Phase A: approximate (hi*hi) bucket maxes -> tau = 10th bucket max - slack.
// Phase B: exact 3-pass scores, collect survivors >= tau into LDS lists.
__global__ __launch_bounds__(256, 1) void attn2(
    const unsigned short* __restrict__ qhi, const unsigned short* __restrict__ qlo,
    const unsigned short* __restrict__ khf_hi, const unsigned short* __restrict__ khf_lo,
    const unsigned int* __restrict__ bits2,
    int* __restrict__ scnt, float* __restrict__ sval, int* __restrict__ sidx) {
    int h = blockIdx.x >> 1, half = blockIdx.x & 1;
    int rt = blockIdx.y; int r0 = rt * 64;
    int tid = threadIdx.x;
    int w = tid >> 6, lane = tid & 63;
    int n = lane & 15, quad = lane >> 4;
    int q4 = quad * 4;
    int at0 = half * 256 + w * 64;          // a-tile base (16 a per tile)
    int hbase = h * 512;

    __shared__ float bmax[64][67];
    __shared__ float taus[64];
    __shared__ int   lcnt[64];
    __shared__ float lval[64][CAP];
    __shared__ int   lidx[64][CAP];

    const bf16x8* kh8 = (const bf16x8*)khf_hi;
    const bf16x8* kl8 = (const bf16x8*)khf_lo;
    const uint2* b2 = (const uint2*)bits2;

    // Preload A-frags: 4 m-tiles x 2 k-chunks, hi+lo
    bf16x8 Ah[4][2], Al[4][2];
#pragma unroll
    for (int mt = 0; mt < 4; ++mt)
#pragma unroll
        for (int c = 0; c < 2; ++c) {
            size_t off = ((size_t)h * N_RNA + r0 + mt * 16 + n) * 64 + c * 32 + quad * 8;
            Ah[mt][c] = *(const bf16x8*)(qhi + off);
            Al[mt][c] = *(const bf16x8*)(qlo + off);
        }

    float mx[4][4];
#pragma unroll
    for (int mt = 0; mt < 4; ++mt)
#pragma unroll
        for (int i = 0; i < 4; ++i) mx[mt][i] = 0.f;

    // ---------------- phase A: approximate (hi*hi) bucket maxes ----------------
#pragma unroll 2
    for (int t = 0; t < 64; ++t) {
        int at = at0 + t;
        size_t bidx = ((size_t)hbase + at) * 128 + lane;
        bf16x8 Bh0 = kh8[bidx];
        bf16x8 Bh1 = kh8[bidx + 64];
        uint2 bl = b2[(size_t)rt * N_ATAC + at * 16 + n];

        f32x4 S[4];
#pragma unroll
        for (int mt = 0; mt < 4; ++mt) {
            f32x4 s = {0.f, 0.f, 0.f, 0.f};
            s = mfma16(Ah[mt][0], Bh0, s);
            s = mfma16(Ah[mt][1], Bh1, s);
            S[mt] = s;
        }
#pragma unroll
        for (int mt = 0; mt < 4; ++mt) {
            unsigned int bw = (mt < 2) ? bl.x : bl.y;
            unsigned int sh = bw >> (((mt & 1) << 4) + q4);
#pragma unroll
            for (int i = 0; i < 4; ++i) {
                float v = ((sh >> i) & 1) ? S[mt][i] : 0.f;
                mx[mt][i] = fmaxf(mx[mt][i], v);
            }
        }
    }

    {
        int b = w * 16 + n;
#pragma unroll
        for (int mt = 0; mt < 4; ++mt)
#pragma unroll
            for (int i = 0; i < 4; ++i) bmax[mt * 16 + q4 + i][b] = mx[mt][i];
    }
    __syncthreads();
    if (tid < 64) {
        int row = tid;
        float t10 = 0.f;
        for (int pass = 0; pass < 10; ++pass) {
            float best = -1.f; int bj = 0;
            for (int j = 0; j < 64; ++j) {
                float v = bmax[row][j];
                if (v > best) { best = v; bj = j; }
            }
            bmax[row][bj] = -1.f;
            t10 = best;
        }
        taus[row] = t10 - TAU_EPS;
    } else if (tid < 128) {
        lcnt[tid - 64] = 0;
    }
    __syncthreads();

    float tau[4][4];
#pragma unroll
    for (int mt = 0; mt < 4; ++mt)
#pragma unroll
        for (int i = 0; i < 4; ++i) tau[mt][i] = taus[mt * 16 + q4 + i];

    // ---------------- phase B: exact scores, collect survivors ----------------
#pragma unroll 2
    for (int t = 0; t < 64; ++t) {
        int at = at0 + t;
        size_t bidx = ((size_t)hbase + at) * 128 + lane;
        bf16x8 Bh0 = kh8[bidx];
        bf16x8 Bh1 = kh8[bidx + 64];
        bf16x8 Bl0 = kl8[bidx];
        bf16x8 Bl1 = kl8[bidx + 64];
        uint2 bl = b2[(size_t)rt * N_ATAC + at * 16 + n];

        f32x4 S[4];
#pragma unroll
        for (int mt = 0; mt < 4; ++mt) {
            f32x4 s = {0.f, 0.f, 0.f, 0.f};
            s = mfma16(Ah[mt][0], Bh0, s);
            s = mfma16(Ah[mt][1], Bh1, s);
            s = mfma16(Ah[mt][0], Bl0, s);
            s = mfma16(Ah[mt][1], Bl1, s);
            s = mfma16(Al[mt][0], Bh0, s);
            s = mfma16(Al[mt][1], Bh1, s);
            S[mt] = s;
        }
        int a16 = at * 16 + n;
#pragma unroll
        for (int mt = 0; mt < 4; ++mt) {
            unsigned int bw = (mt < 2) ? bl.x : bl.y;
            unsigned int sh = bw >> (((mt & 1) << 4) + q4);
#pragma unroll
            for (int i = 0; i < 4; ++i) {
                if (((sh >> i) & 1) && S[mt][i] >= tau[mt][i]) {
                    int row = mt * 16 + q4 + i;
                    int pos = atomicAdd(&lcnt[row], 1);
                    if (pos < CAP) { lval[row][pos] = S[mt][i]; lidx[row][pos] = a16; }
                }
            }
        }
    }
    __syncthreads();

    // bulk write: block exclusively owns slot ((h*4096 + r)*2 + half)
    if (tid < 64) {
        int c = lcnt[tid]; if (c > CAP) c = CAP;
        scnt[((size_t)h * N_RNA + r0 + tid) * 2 + half] = c;
    }
    {
        int row = tid >> 2, j0 = tid & 3;
        int c = lcnt[row]; if (c > CAP) c = CAP;
        size_t slot = ((size_t)h * N_RNA + r0 + row) * 2 + half;
        for (int j = j0; j < c; j += 4) {
            sval[slot * CAP + j] = lval[row][j];
            sidx[slot * CAP + j] = lidx[row][j];
        }
    }
}

// ---------------------------------------------------------------- K3: merge survivors + sigmoid + softmax + threshold
__global__ __launch_bounds__(64) void topk_finalize(
    const int* __restrict__ scnt, const float* __restrict__ sval, const int* __restrict__ sidx,
    float* __restrict__ sel_w, int* __restrict__ sel_i) {
    int p = blockIdx.x * 64 + threadIdx.x;
    if (p >= NH * N_RNA) return;
    float mv[10]; int mi[10];
#pragma unroll
    for (int s = 0; s < 10; ++s) { mv[s] = NEG_INF; mi[s] = 0; }
    float mn = NEG_INF; int ms = 0;
    for (int q = 0; q < 2; ++q) {
        size_t slot = (size_t)p * 2 + q;
        int c = scnt[slot]; if (c > CAP) c = CAP;
        for (int j = 0; j < c; ++j) {
            float v = sval[slot * CAP + j];
            if (v > mn) topk_insert(mv, mi, mn, ms, v, sidx[slot * CAP + j]);
        }
    }
    float sg[10]; float es[10]; float sum = 0.f;
#pragma unroll
    for (int s = 0; s < 10; ++s) {
        sg[s] = 1.0f / (1.0f + expf(-mv[s]));
        es[s] = expf(sg[s]);
        sum += es[s];
    }
    float inv = 1.0f / sum;
    int base = p * 16;
#pragma unroll
    for (int s = 0; s < 10; ++s) {
        float w = es[s] * inv;
        if (!(sg[s] > 0.8f)) w = 0.f;
        sel_w[base + s] = w;
        sel_i[base + s] = mi[s];
    }
}

// ---------------------------------------------------------------- K4a: rna_agg gather
__global__ __launch_bounds__(256) void rna_gather(
    const float* __restrict__ sel_w, const int* __restrict__ sel_i,
    const float* __restrict__ v_a, float* __restrict__ rna_agg) {
    int gid = blockIdx.x * 256 + threadIdx.x;
    int r = gid >> 4, g = gid & 15;
    int c0 = g * 8; int h = g >> 3;
    int base = (h * N_RNA + r) * 16;
    float4 a0 = make_float4(0.f, 0.f, 0.f, 0.f);
    float4 a1 = make_float4(0.f, 0.f, 0.f, 0.f);
    for (int i = 0; i < TOPK; ++i) {
        float w = sel_w[base + i];
        int idx = sel_i[base + i];
        const float4* vp = (const float4*)(v_a + (size_t)idx * HID + c0);
        float4 v0 = vp[0], v1 = vp[1];
        a0.x += w * v0.x; a0.y += w * v0.y; a0.z += w * v0.z; a0.w += w * v0.w;
        a1.x += w * v1.x; a1.y += w * v1.y; a1.z += w * v1.z; a1.w += w * v1.w;
    }
    float4* op = (float4*)(rna_agg + (size_t)r * HID + c0);
    op[0] = a0; op[1] = a1;
}

// ---------------------------------------------------------------- K4b: atac_agg scatter (atomics)
__global__ __launch_bounds__(256) void atac_scatter(
    const float* __restrict__ sel_w, const int* __restrict__ sel_i,
    const float* __restrict__ v_r, float* __restrict__ atac_agg) {
    int wid = threadIdx.x >> 6, lane = threadIdx.x & 63;
    int p = blockIdx.x * 4 + wid;
    int h = p >> 12; int r = p & 4095;
    float v = v_r[(size_t)r * HID + h * 64 + lane];
    int base = p * 16;
    for (int i = 0; i < TOPK; ++i) {
        float w = sel_w[base + i];
        if (w != 0.f) {
            int idx = sel_i[base + i];
            atomicAdd(&atac_agg[(size_t)idx * HID + h * 64 + lane], w * v);
        }
    }
}

// ---------------------------------------------------------------- K5: C = A@W1 + X@W2 + bias (both outputs)
__global__ __launch_bounds__(256) void out_gemm(
    const float* __restrict__ rna_agg, const float* __restrict__ x_rna,
    const float* __restrict__ Wr1, const float* __restrict__ Wr2, const float* __restrict__ brf,
    const float* __restrict__ atac_agg, const float* __restrict__ x_atac,
    const float* __restrict__ Wa1, const float* __restrict__ Wa2, const float* __restrict__ baf,
    float* __restrict__ out_r, float* __restrict__ out_a) {
    int bx = blockIdx.x;
    const float *A, *X, *W1, *W2, *bias; float* C;
    int rb;
    if (bx < 512) { A = rna_agg; X = x_rna; W1 = Wr1; W2 = Wr2; bias = brf; C = out_r; rb = bx; }
    else { A = atac_agg; X = x_atac; W1 = Wa1; W2 = Wa2; bias = baf; C = out_a; rb = bx - 512; }
    int r = rb * 8 + (threadIdx.x >> 5);
    int cg = threadIdx.x & 31; int c0 = cg * 4;
    float4 acc = *(const float4*)&bias[c0];
    const float* a = A + (size_t)r * HID;
#pragma unroll 4
    for (int k = 0; k < 128; ++k) {
        float av = a[k];
        float4 w = *(const float4*)&W1[(size_t)k * HID + c0];
        acc.x += av * w.x; acc.y += av * w.y; acc.z += av * w.z; acc.w += av * w.w;
    }
    const float* x = X + (size_t)r * IN_C;
#pragma unroll 4
    for (int k = 0; k < 256; ++k) {
        float xv = x[k];
        float4 w = *(const float4*)&W2[(size_t)k * HID + c0];
        acc.x += xv * w.x; acc.y += xv * w.y; acc.z += xv * w.z; acc.w += xv * w.w;
    }
    *(float4*)&C[(size_t)r * HID + c0] = acc;
}

// ---------------------------------------------------------------- launch
extern "C" void kernel_launch(void* const* d_in, const int* in_sizes, int n_in,
                              void* d_out, int out_size, void* d_ws, size_t ws_size,
                              hipStream_t stream) {
    const float* x_rna = (const float*)d_in[0];
    const float* x_atac = (const float*)d_in[1];
    const float* mask = (const float*)d_in[2];
    const float* Wq = (const float*)d_in[3];  const float* bq = (const float*)d_in[4];
    const float* Wk = (const float*)d_in[5];  const float* bk = (const float*)d_in[6];
    const float* Wvr = (const float*)d_in[7]; const float* bvr = (const float*)d_in[8];
    const float* Wva = (const float*)d_in[9]; const float* bva = (const float*)d_in[10];
    const float* Wor = (const float*)d_in[11]; const float* bor = (const float*)d_in[12];
    const float* Woa = (const float*)d_in[13]; const float* boa = (const float*)d_in[14];
    const float* Wsr = (const float*)d_in[15]; const float* bsr = (const float*)d_in[16];
    const float* Wsa = (const float*)d_in[17]; const float* bsa = (const float*)d_in[18];
    const float* Wdr = (const float*)d_in[19]; const float* bdr = (const float*)d_in[20];
    const float* Wda = (const float*)d_in[21]; const float* bda = (const float*)d_in[22];

    float* out_r = (float*)d_out;
    float* out_a = out_r + N_RNA * HID;

    float* ws = (float*)d_ws;
    unsigned short* qhi = (unsigned short*)ws;            // 2*4096*64 us
    unsigned short* qlo = qhi + 524288;
    unsigned short* khf_hi = qlo + 524288;                // 2*8192*64 us (frag layout)
    unsigned short* khf_lo = khf_hi + 1048576;
    unsigned int* bits2 = (unsigned int*)(ws + 1572864);  // 64*8192*2 uint
    float* v_r = ws + 1572864 + 1048576;                  // 4096x128
    float* v_a = v_r + 524288;                            // 8192x128
    float* Wr1 = v_a + 1048576;                           // 128x128
    float* Wr2 = Wr1 + 16384;                             // 256x128
    float* brf = Wr2 + 32768;                             // 128
    float* Wa1 = brf + 128;                               // 128x128
    float* Wa2 = Wa1 + 16384;                             // 256x128
    float* baf = Wa2 + 32768;                             // 128
    int* scnt = (int*)(baf + 128);                        // 8192*2 ints (pad to 16384)
    float* sval = (float*)scnt + 16384;                   // 16384*64
    int* sidx = (int*)(sval + 1048576);                   // 16384*64
    float* sel_w = (float*)sidx + 1048576;                // 8192*16
    int* sel_i = (int*)(sel_w + 131072);                  // 8192*16
    float* rna_agg = (float*)sel_i + 131072;              // 4096x128
    float* atac_agg = rna_agg + 524288;                   // 8192x128

    hipLaunchKernelGGL(prep_bits, dim3(2048), dim3(256), 0, stream, mask, bits2);
    hipLaunchKernelGGL(prep_misc, dim3(1426), dim3(256), 0, stream,
                       atac_agg, scnt,
                       Wor, bor, Woa, boa, Wsr, bsr, Wsa, bsa, Wdr, bdr, Wda, bda,
                       Wr1, Wr2, brf, Wa1, Wa2, baf);
    hipLaunchKernelGGL(proj_gemm, dim3(128, 4), dim3(256), 0, stream,
                       x_rna, x_atac, Wq, bq, Wk, bk, Wvr, bvr, Wva, bva,
                       qhi, qlo, khf_hi, khf_lo, v_r, v_a);
    hipLaunchKernelGGL(attn2, dim3(4, 64), dim3(256), 0, stream,
                       qhi, qlo, khf_hi, khf_lo, bits2, scnt, sval, sidx);
    hipLaunchKernelGGL(topk_finalize, dim3(128), dim3(64), 0, stream,
                       scnt, sval, sidx, sel_w, sel_i);
    hipLaunchKernelGGL(rna_gather, dim3(256), dim3(256), 0, stream, sel_w, sel_i, v_a, rna_agg);
    hipLaunchKernelGGL(atac_scatter, dim3(2048), dim3(256), 0, stream, sel_w, sel_i, v_r, atac_agg);
    hipLaunchKernelGGL(out_gemm, dim3(1536), dim3(256), 0, stream,
                       rna_agg, x_rna, Wr1, Wr2, brf,
                       atac_agg, x_atac, Wa1, Wa2, baf, out_r, out_a);
}